// Round 6
// baseline (129.433 us; speedup 1.0000x reference)
//
#include <hip/hip_runtime.h>

#define B 16
#define N 1024
#define NF 128
#define NL 3
#define AH 64
#define HC 192   // NL*AH
#define FCH 128
#define NC 10
#define L2E 1.44269504088896f

typedef __attribute__((ext_vector_type(8))) short bf16x8;
typedef __attribute__((ext_vector_type(4))) float f32x4;
typedef __attribute__((ext_vector_type(4))) unsigned int u32x4;

static __device__ __forceinline__ unsigned short f2bf(float f) {
  unsigned int x = __builtin_bit_cast(unsigned int, f);
  return (unsigned short)((x + 0x7fffu + ((x >> 16) & 1u)) >> 16);   // RNE
}
static __device__ __forceinline__ float bf2f(unsigned short u) {
  unsigned int x = ((unsigned int)u) << 16;
  return __builtin_bit_cast(float, x);
}

// ---------------------------------------------------------------------------
// k_fm: blocks with bid%3==0 = feat (64 rows, split-bf16 MFMA GEMM -> h_t
// bf16 transposed + f1/f2 f32 pre-scaled by log2e; Ws converted in-block);
// other blocks = adj bitmask via coalesced float4 + shfl nibble packing.
// grid = 768 x 256.
// ---------------------------------------------------------------------------
__global__ __launch_bounds__(256) void k_fm(
    const float* __restrict__ x, const float* __restrict__ adj,
    const float* __restrict__ Ws, const float* __restrict__ a1,
    const float* __restrict__ a2, unsigned short* __restrict__ h_t,
    float* __restrict__ f1g, float* __restrict__ f2g,
    unsigned short* __restrict__ msk)
{
  const int bid = blockIdx.x, t = threadIdx.x;

  if (bid % 3 != 0) {                     // ---- mask role: 32 adj rows ----
    const int mid = bid - bid / 3 - 1;    // 0..511
    const int wv = t >> 6, lane = t & 63;
    const int r0 = mid * 32 + wv * 8;
    #pragma unroll 2
    for (int rr = 0; rr < 8; ++rr) {
      const int row = r0 + rr;
      const float* ap = adj + ((size_t)row << 10);
      #pragma unroll
      for (int c = 0; c < 4; ++c) {
        const float4 v = *(const float4*)&ap[c * 256 + lane * 4];
        unsigned int nib = (v.x != 0.f ? 1u : 0u) | (v.y != 0.f ? 2u : 0u)
                         | (v.z != 0.f ? 4u : 0u) | (v.w != 0.f ? 8u : 0u);
        const unsigned int n1 = __shfl_down(nib, 1);
        const unsigned int n2 = __shfl_down(nib, 2);
        const unsigned int n3 = __shfl_down(nib, 3);
        if ((lane & 3) == 0)
          msk[((size_t)row << 6) + c * 16 + (lane >> 2)] =
              (unsigned short)(nib | (n1 << 4) | (n2 << 8) | (n3 << 12));
      }
    }
    return;
  }

  // ---- feat role ----
  __shared__ unsigned short wlds[2][HC][40];   // hi/lo k-slab
  __shared__ unsigned short hlds[HC][72];      // transpose buffer
  const int fid = bid / 3;
  const int n0g = fid * 64;
  const int gb = n0g >> 10, nl0 = n0g & 1023;
  const int wv = t >> 6, lane = t & 63;
  const int lr = lane & 15, lg = lane >> 4;
  const int row = n0g + wv * 16 + lr;

  f32x4 acc[12];
  #pragma unroll
  for (int n = 0; n < 12; ++n) acc[n] = (f32x4){0.f, 0.f, 0.f, 0.f};

  for (int k0 = 0; k0 < NF; k0 += 32) {
    __syncthreads();
    for (int p = t; p < HC * 32; p += 256) {   // Ws -> hi/lo bf16 LDS
      const int k = p / HC, col = p - k * HC;
      const float wv_ = Ws[(size_t)((col >> 6) * NF + k0 + k) * AH + (col & 63)];
      const unsigned short hi = f2bf(wv_);
      wlds[0][col][k] = hi;
      wlds[1][col][k] = f2bf(wv_ - bf2f(hi));
    }
    __syncthreads();

    const float4 q0 = *(const float4*)&x[(size_t)row * NF + k0 + lg * 8];
    const float4 q1 = *(const float4*)&x[(size_t)row * NF + k0 + lg * 8 + 4];
    const float xv[8] = {q0.x, q0.y, q0.z, q0.w, q1.x, q1.y, q1.z, q1.w};
    bf16x8 xhi, xlo;
    #pragma unroll
    for (int e = 0; e < 8; ++e) {
      const unsigned short hi = f2bf(xv[e]);
      xhi[e] = (short)hi;
      xlo[e] = (short)f2bf(xv[e] - bf2f(hi));
    }
    #pragma unroll
    for (int n = 0; n < 12; ++n) {
      const int col = n * 16 + lr;
      const bf16x8 whi = *(const bf16x8*)&wlds[0][col][lg * 8];
      const bf16x8 wlo = *(const bf16x8*)&wlds[1][col][lg * 8];
      acc[n] = __builtin_amdgcn_mfma_f32_16x16x32_bf16(xhi, whi, acc[n], 0, 0, 0);
      acc[n] = __builtin_amdgcn_mfma_f32_16x16x32_bf16(xhi, wlo, acc[n], 0, 0, 0);
      acc[n] = __builtin_amdgcn_mfma_f32_16x16x32_bf16(xlo, whi, acc[n], 0, 0, 0);
    }
  }

  // f1/f2 (exact f32), pre-scaled by log2e
  float s1[3][4], s2[3][4];
  #pragma unroll
  for (int l = 0; l < 3; ++l)
    #pragma unroll
    for (int r = 0; r < 4; ++r) { s1[l][r] = 0.f; s2[l][r] = 0.f; }
  #pragma unroll
  for (int n = 0; n < 12; ++n) {
    const int col = n * 16 + lr;
    const float a1v = a1[col] * L2E, a2v = a2[col] * L2E;
    const int l = n >> 2;
    #pragma unroll
    for (int r = 0; r < 4; ++r) {
      s1[l][r] += acc[n][r] * a1v;
      s2[l][r] += acc[n][r] * a2v;
    }
  }
  #pragma unroll
  for (int off = 1; off < 16; off <<= 1)
    #pragma unroll
    for (int l = 0; l < 3; ++l)
      #pragma unroll
      for (int r = 0; r < 4; ++r) {
        s1[l][r] += __shfl_xor(s1[l][r], off);
        s2[l][r] += __shfl_xor(s2[l][r], off);
      }
  if (lr == 0) {
    #pragma unroll
    for (int l = 0; l < 3; ++l)
      #pragma unroll
      for (int r = 0; r < 4; ++r) {
        const int rw = n0g + wv * 16 + lg * 4 + r;
        f1g[(size_t)l * (B * N) + rw] = s1[l][r];
        f2g[(size_t)l * (B * N) + rw] = s2[l][r];
      }
  }

  // h_t: pack bf16 + LDS transpose + coalesced store
  #pragma unroll
  for (int n = 0; n < 12; ++n) {
    const int col = n * 16 + lr;
    #pragma unroll
    for (int rp = 0; rp < 2; ++rp) {
      const unsigned int pr = (unsigned int)f2bf(acc[n][rp * 2]) |
                              ((unsigned int)f2bf(acc[n][rp * 2 + 1]) << 16);
      *(unsigned int*)&hlds[col][wv * 16 + lg * 4 + rp * 2] = pr;
    }
  }
  __syncthreads();
  #pragma unroll
  for (int pass = 0; pass < 6; ++pass) {
    const int col = pass * 32 + (t >> 3);
    const int r8 = (t & 7) * 8;
    *(uint4*)&h_t[(((size_t)(gb * HC + col)) << 10) + nl0 + r8] =
        *(const uint4*)&hlds[col][r8];
  }
}

// ---------------------------------------------------------------------------
// k_att: fused 3-layer GAT attention + MFMA PV + ones-column denominator +
// relu + pool. Register-double-buffered B-frag/mask prefetch; XCD-chunked
// swizzle. grid = 512 blocks x 384 threads (6 waves = 2 row-groups x 3 layers),
// wave owns 16 complete rows.
// ---------------------------------------------------------------------------
__global__ __launch_bounds__(384, 3) void k_att(
    const unsigned char* __restrict__ msk8, const unsigned short* __restrict__ h_t,
    const float* __restrict__ f1, const float* __restrict__ f2,
    float* __restrict__ pooled)
{
  const int bid = blockIdx.x;
  const int blk = (bid & 7) * 64 + (bid >> 3);   // XCD chunk: 2 batches per XCD
  const int b = blk >> 5;
  const int t = threadIdx.x;
  const int w = t >> 6, lane = t & 63;
  const int l = w >> 1, rg = w & 1;
  const int i0 = (blk & 31) * 32 + rg * 16;
  const int lr = lane & 15, lg = lane >> 4;

  __shared__ float uvt[NL][2][N];              // 24 KB u/v tables

  // prologue: layer-l tables (rg=0 waves write) + unmasked max (all waves)
  const float* f2p = f2 + (size_t)l * (B * N) + b * N;
  const int jb = lane * 16;
  float fv[16];
  {
    const float4 c0 = *(const float4*)&f2p[jb];
    const float4 c1 = *(const float4*)&f2p[jb + 4];
    const float4 c2 = *(const float4*)&f2p[jb + 8];
    const float4 c3 = *(const float4*)&f2p[jb + 12];
    fv[0]=c0.x; fv[1]=c0.y; fv[2]=c0.z; fv[3]=c0.w;
    fv[4]=c1.x; fv[5]=c1.y; fv[6]=c1.z; fv[7]=c1.w;
    fv[8]=c2.x; fv[9]=c2.y; fv[10]=c2.z; fv[11]=c2.w;
    fv[12]=c3.x; fv[13]=c3.y; fv[14]=c3.z; fv[15]=c3.w;
  }
  float mx = fv[0];
  #pragma unroll
  for (int e = 1; e < 16; ++e) mx = fmaxf(mx, fv[e]);
  #pragma unroll
  for (int off = 1; off < 64; off <<= 1) mx = fmaxf(mx, __shfl_xor(mx, off));

  if (rg == 0) {
    float ue[16], ve[16];
    #pragma unroll
    for (int e = 0; e < 16; ++e) {
      ue[e] = exp2f(fv[e]);
      ve[e] = exp2f(0.2f * fv[e]);
    }
    #pragma unroll
    for (int q = 0; q < 4; ++q) {
      *(float4*)&uvt[l][0][jb + q * 4] = (float4){ue[q*4], ue[q*4+1], ue[q*4+2], ue[q*4+3]};
      *(float4*)&uvt[l][1][jb + q * 4] = (float4){ve[q*4], ve[q*4+1], ve[q*4+2], ve[q*4+3]};
    }
  }
  __syncthreads();

  const float f1r = f1[(size_t)l * (B * N) + b * N + i0 + lr];
  const float tts = f1r + mx;
  const float sr = fmaxf(tts, 0.f) + 0.2f * fminf(tts, 0.f);  // valid upper bound
  const float A = exp2f(f1r - sr);
  const float C = exp2f(0.2f * f1r - sr);
  const float T = exp2f(-f1r);                 // u_j > T  <=>  f1+f2 > 0

  const unsigned char* mrow = msk8 + ((size_t)(b * N + i0 + lr) << 7);
  const unsigned short* hb = h_t + (((size_t)(b * HC + l * 64)) << 10);
  const int klane = lg * 8;
  const float* ut = &uvt[l][0][0];
  const float* vt = &uvt[l][1][0];
  const bf16x8 ones = {(short)0x3F80, (short)0x3F80, (short)0x3F80, (short)0x3F80,
                       (short)0x3F80, (short)0x3F80, (short)0x3F80, (short)0x3F80};

  f32x4 acc[4];
  #pragma unroll
  for (int n = 0; n < 4; ++n) acc[n] = (f32x4){0.f, 0.f, 0.f, 0.f};
  f32x4 accd = (f32x4){0.f, 0.f, 0.f, 0.f};

#define LOADJ(BUF, MW, J) {                                                   \
    const int jj = (J) & (N - 1);                                             \
    MW = *(const unsigned long long*)&mrow[jj >> 3];                          \
    _Pragma("unroll")                                                         \
    for (int q = 0; q < 8; ++q) {                                             \
      const int ks = q >> 2, n = q & 3;                                       \
      BUF[q] = *(const bf16x8*)&hb[(((size_t)(n * 16 + lr)) << 10) + jj +     \
                                   ks * 32 + klane];                          \
    } }

#define COMPJ(BUF, MW, J) {                                                   \
    _Pragma("unroll")                                                         \
    for (int ks = 0; ks < 2; ++ks) {                                          \
      const int kb = (J) + ks * 32 + klane;                                   \
      const float4 u0 = *(const float4*)&ut[kb];                              \
      const float4 u1 = *(const float4*)&ut[kb + 4];                          \
      const float4 v0 = *(const float4*)&vt[kb];                              \
      const float4 v1 = *(const float4*)&vt[kb + 4];                          \
      const float uu[8] = {u0.x, u0.y, u0.z, u0.w, u1.x, u1.y, u1.z, u1.w};   \
      const float vv[8] = {v0.x, v0.y, v0.z, v0.w, v1.x, v1.y, v1.z, v1.w};   \
      const unsigned int wb = (unsigned int)((MW) >> (ks * 32 + klane));      \
      unsigned int pk[4];                                                     \
      _Pragma("unroll")                                                       \
      for (int ep = 0; ep < 4; ++ep) {                                        \
        unsigned int pr[2];                                                   \
        _Pragma("unroll")                                                     \
        for (int h = 0; h < 2; ++h) {                                         \
          const int e = ep * 2 + h;                                           \
          const bool pos = uu[e] > T;                                         \
          const float z = pos ? uu[e] : vv[e];                                \
          const float wgt = pos ? A : C;                                      \
          float p = wgt * z;                                                  \
          p = ((wb >> e) & 1u) ? p : 0.f;                                     \
          pr[h] = __builtin_bit_cast(unsigned int, p) + 0x8000u;              \
        }                                                                     \
        pk[ep] = __builtin_amdgcn_perm(pr[1], pr[0], 0x07060302u);            \
      }                                                                       \
      const u32x4 pkv = {pk[0], pk[1], pk[2], pk[3]};                         \
      const bf16x8 av = __builtin_bit_cast(bf16x8, pkv);                      \
      _Pragma("unroll")                                                       \
      for (int n = 0; n < 4; ++n)                                             \
        acc[n] = __builtin_amdgcn_mfma_f32_16x16x32_bf16(av, BUF[ks * 4 + n], \
                                                         acc[n], 0, 0, 0);    \
      accd = __builtin_amdgcn_mfma_f32_16x16x32_bf16(av, ones, accd, 0, 0, 0);\
    } }

  bf16x8 bA[8], bB[8];
  unsigned long long mwA, mwB;
  LOADJ(bA, mwA, 0);
  for (int j0 = 0; j0 < N; j0 += 128) {
    LOADJ(bB, mwB, j0 + 64);
    COMPJ(bA, mwA, j0);
    LOADJ(bA, mwA, j0 + 128);      // wraps harmlessly on last iter
    COMPJ(bB, mwB, j0 + 64);
  }
#undef LOADJ
#undef COMPJ

  // epilogue: rows lg*4+r owned by this lane's acc regs; denom from accd
  float dn[4];
  #pragma unroll
  for (int r = 0; r < 4; ++r) dn[r] = 1.f / fmaxf(accd[r], 1e-37f);

  #pragma unroll
  for (int n = 0; n < 4; ++n) {
    float csum = 0.f;
    #pragma unroll
    for (int r = 0; r < 4; ++r) csum += fmaxf(acc[n][r] * dn[r], 0.f);
    csum += __shfl_xor(csum, 16);
    csum += __shfl_xor(csum, 32);
    if (lg == 0) atomicAdd(&pooled[b * HC + l * 64 + n * 16 + lr], csum);
  }
}

// ---------------------------------------------------------------------------
// k_head: mean + FC1(relu) + FC2 + softmax.  grid = B.
// ---------------------------------------------------------------------------
__global__ __launch_bounds__(192) void k_head(
    const float* __restrict__ pooled_sums, const float* __restrict__ W1,
    const float* __restrict__ b1, const float* __restrict__ W2,
    const float* __restrict__ b2, float* __restrict__ out)
{
  const int b = blockIdx.x, t = threadIdx.x;
  __shared__ float pooled[HC];
  __shared__ float z[FCH];
  __shared__ float logits[NC];

  if (t < HC) pooled[t] = pooled_sums[b * HC + t] * (1.f / (float)N);
  __syncthreads();

  if (t < FCH) {
    float a = b1[t];
    #pragma unroll 4
    for (int f = 0; f < HC; ++f) a += pooled[f] * W1[(size_t)f * FCH + t];
    z[t] = a > 0.f ? a : 0.f;
  }
  __syncthreads();

  if (t < NC) {
    float a = b2[t];
    #pragma unroll 4
    for (int f = 0; f < FCH; ++f) a += z[f] * W2[(size_t)f * NC + t];
    logits[t] = a;
  }
  __syncthreads();

  if (t == 0) {
    float mxl = logits[0];
    for (int c = 1; c < NC; ++c) mxl = fmaxf(mxl, logits[c]);
    float e[NC], sum = 0.f;
    for (int c = 0; c < NC; ++c) { e[c] = __expf(logits[c] - mxl); sum += e[c]; }
    const float inv = 1.f / sum;
    for (int c = 0; c < NC; ++c) out[b * NC + c] = e[c] * inv;
  }
}

// ---------------------------------------------------------------------------
extern "C" void kernel_launch(void* const* d_in, const int* in_sizes, int n_in,
                              void* d_out, int out_size, void* d_ws, size_t ws_size,
                              hipStream_t stream)
{
  const float* x   = (const float*)d_in[0];
  const float* adj = (const float*)d_in[1];
  const float* Ws  = (const float*)d_in[2];
  const float* a1  = (const float*)d_in[3];
  const float* a2  = (const float*)d_in[4];
  const float* W1  = (const float*)d_in[5];
  const float* b1  = (const float*)d_in[6];
  const float* W2  = (const float*)d_in[7];
  const float* b2  = (const float*)d_in[8];
  float* out = (float*)d_out;

  // workspace layout (16B aligned chunks)
  unsigned short* h_t   = (unsigned short*)d_ws;                       // 6.29 MB
  float*          f1    = (float*)(h_t + (size_t)B * HC * N);          // 196 KB
  float*          f2    = f1 + (size_t)NL * B * N;                     // 196 KB
  float*          pooled= f2 + (size_t)NL * B * N;                     // 12 KB
  unsigned short* msk   = (unsigned short*)(pooled + B * HC + 16);     // 2 MB

  hipMemsetAsync(pooled, 0, (size_t)B * HC * sizeof(float), stream);
  k_fm  <<<768, 256, 0, stream>>>(x, adj, Ws, a1, a2, h_t, f1, f2, msk);
  k_att <<<512, 384, 0, stream>>>((const unsigned char*)msk, h_t, f1, f2, pooled);
  k_head<<<B, 192, 0, stream>>>(pooled, W1, b1, W2, b2, out);
}

// Round 7
// 109.988 us; speedup vs baseline: 1.1768x; 1.1768x over previous
//
#include <hip/hip_runtime.h>

#define B 16
#define N 1024
#define NF 128
#define NL 3
#define AH 64
#define HC 192   // NL*AH
#define FCH 128
#define NC 10
#define L2E 1.44269504088896f

typedef __attribute__((ext_vector_type(8))) short bf16x8;
typedef __attribute__((ext_vector_type(4))) float f32x4;
typedef __attribute__((ext_vector_type(4))) unsigned int u32x4;

static __device__ __forceinline__ unsigned short f2bf(float f) {
  unsigned int x = __builtin_bit_cast(unsigned int, f);
  return (unsigned short)((x + 0x7fffu + ((x >> 16) & 1u)) >> 16);   // RNE
}
static __device__ __forceinline__ float bf2f(unsigned short u) {
  unsigned int x = ((unsigned int)u) << 16;
  return __builtin_bit_cast(float, x);
}

// ---------------------------------------------------------------------------
// k_wt: Ws -> bf16 hi/lo in MFMA-FRAGMENT order:
//   idx = ((n*4+kf)*64+lane)*8+e ; col=n*16+(lane&15) ; k=kf*32+(lane>>4)*8+e
// so a feat wave loads one fragment as a single coalesced 1KB bf16x8 read.
// Also zeroes pooled. grid = 96 x 256.
// ---------------------------------------------------------------------------
__global__ __launch_bounds__(256) void k_wt(
    const float* __restrict__ Ws, unsigned short* __restrict__ wt_hi,
    unsigned short* __restrict__ wt_lo, float* __restrict__ pooled)
{
  const int idx = blockIdx.x * 256 + threadIdx.x;     // 0..24575
  const int n = idx >> 11;
  const int kf = (idx >> 9) & 3;
  const int lane = (idx >> 3) & 63;
  const int e = idx & 7;
  const int col = n * 16 + (lane & 15);
  const int k = kf * 32 + (lane >> 4) * 8 + e;
  const float w = Ws[(size_t)((col >> 6) * NF + k) * AH + (col & 63)];
  const unsigned short hi = f2bf(w);
  wt_hi[idx] = hi;
  wt_lo[idx] = f2bf(w - bf2f(hi));
  if (idx < B * HC) pooled[idx] = 0.f;
}

// ---------------------------------------------------------------------------
// k_fm: bid%3==0 -> feat (64 rows, split-bf16 MFMA with fragment-order wt
// from global, K=128 fully unrolled, no wt LDS); else -> adj bitmask
// (coalesced float4 + shfl nibble pack). grid = 768 x 256. LDS = 30KB only.
// ---------------------------------------------------------------------------
__global__ __launch_bounds__(256) void k_fm(
    const float* __restrict__ x, const float* __restrict__ adj,
    const unsigned short* __restrict__ wt_hi, const unsigned short* __restrict__ wt_lo,
    const float* __restrict__ a1, const float* __restrict__ a2,
    unsigned short* __restrict__ h_t, float* __restrict__ f1g,
    float* __restrict__ f2g, unsigned short* __restrict__ msk)
{
  const int bid = blockIdx.x, t = threadIdx.x;

  if (bid % 3 != 0) {                     // ---- mask role: 32 adj rows ----
    const int mid = bid - bid / 3 - 1;    // 0..511
    const int wv = t >> 6, lane = t & 63;
    const int r0 = mid * 32 + wv * 8;
    #pragma unroll 2
    for (int rr = 0; rr < 8; ++rr) {
      const int row = r0 + rr;
      const float* ap = adj + ((size_t)row << 10);
      #pragma unroll
      for (int c = 0; c < 4; ++c) {
        const float4 v = *(const float4*)&ap[c * 256 + lane * 4];
        unsigned int nib = (v.x != 0.f ? 1u : 0u) | (v.y != 0.f ? 2u : 0u)
                         | (v.z != 0.f ? 4u : 0u) | (v.w != 0.f ? 8u : 0u);
        const unsigned int n1 = __shfl_down(nib, 1);
        const unsigned int n2 = __shfl_down(nib, 2);
        const unsigned int n3 = __shfl_down(nib, 3);
        if ((lane & 3) == 0)
          msk[((size_t)row << 6) + c * 16 + (lane >> 2)] =
              (unsigned short)(nib | (n1 << 4) | (n2 << 8) | (n3 << 12));
      }
    }
    return;
  }

  // ---- feat role: rows n0g..n0g+63 ----
  __shared__ unsigned short hlds[HC][80];      // transpose buffer, 30KB
  const int fid = bid / 3;
  const int n0g = fid * 64;
  const int gb = n0g >> 10, nl0 = n0g & 1023;
  const int wv = t >> 6, lane = t & 63;
  const int lr = lane & 15, lg = lane >> 4;
  const int row = n0g + wv * 16 + lr;

  // whole x row (128 floats) -> split bf16, kept in registers
  bf16x8 xhi[4], xlo[4];
  #pragma unroll
  for (int kf = 0; kf < 4; ++kf) {
    const float4 q0 = *(const float4*)&x[(size_t)row * NF + kf * 32 + lg * 8];
    const float4 q1 = *(const float4*)&x[(size_t)row * NF + kf * 32 + lg * 8 + 4];
    const float xv[8] = {q0.x, q0.y, q0.z, q0.w, q1.x, q1.y, q1.z, q1.w};
    #pragma unroll
    for (int e = 0; e < 8; ++e) {
      const unsigned short hi = f2bf(xv[e]);
      xhi[kf][e] = (short)hi;
      xlo[kf][e] = (short)f2bf(xv[e] - bf2f(hi));
    }
  }

  f32x4 acc[12];
  #pragma unroll
  for (int n = 0; n < 12; ++n) acc[n] = (f32x4){0.f, 0.f, 0.f, 0.f};

  #pragma unroll
  for (int n = 0; n < 12; ++n) {
    #pragma unroll
    for (int kf = 0; kf < 4; ++kf) {
      const int fo = ((n * 4 + kf) << 9) + lane * 8;
      const bf16x8 whi = *(const bf16x8*)&wt_hi[fo];
      const bf16x8 wlo = *(const bf16x8*)&wt_lo[fo];
      acc[n] = __builtin_amdgcn_mfma_f32_16x16x32_bf16(xhi[kf], whi, acc[n], 0, 0, 0);
      acc[n] = __builtin_amdgcn_mfma_f32_16x16x32_bf16(xhi[kf], wlo, acc[n], 0, 0, 0);
      acc[n] = __builtin_amdgcn_mfma_f32_16x16x32_bf16(xlo[kf], whi, acc[n], 0, 0, 0);
    }
  }

  // f1/f2 (exact f32), pre-scaled by log2e
  float s1[3][4], s2[3][4];
  #pragma unroll
  for (int l = 0; l < 3; ++l)
    #pragma unroll
    for (int r = 0; r < 4; ++r) { s1[l][r] = 0.f; s2[l][r] = 0.f; }
  #pragma unroll
  for (int n = 0; n < 12; ++n) {
    const int col = n * 16 + lr;
    const float a1v = a1[col] * L2E, a2v = a2[col] * L2E;
    const int l = n >> 2;
    #pragma unroll
    for (int r = 0; r < 4; ++r) {
      s1[l][r] += acc[n][r] * a1v;
      s2[l][r] += acc[n][r] * a2v;
    }
  }
  #pragma unroll
  for (int off = 1; off < 16; off <<= 1)
    #pragma unroll
    for (int l = 0; l < 3; ++l)
      #pragma unroll
      for (int r = 0; r < 4; ++r) {
        s1[l][r] += __shfl_xor(s1[l][r], off);
        s2[l][r] += __shfl_xor(s2[l][r], off);
      }
  if (lr == 0) {
    #pragma unroll
    for (int l = 0; l < 3; ++l)
      #pragma unroll
      for (int r = 0; r < 4; ++r) {
        const int rw = n0g + wv * 16 + lg * 4 + r;
        f1g[(size_t)l * (B * N) + rw] = s1[l][r];
        f2g[(size_t)l * (B * N) + rw] = s2[l][r];
      }
  }

  // h_t: pack bf16 + LDS transpose + coalesced store
  #pragma unroll
  for (int n = 0; n < 12; ++n) {
    const int col = n * 16 + lr;
    #pragma unroll
    for (int rp = 0; rp < 2; ++rp) {
      const unsigned int pr = (unsigned int)f2bf(acc[n][rp * 2]) |
                              ((unsigned int)f2bf(acc[n][rp * 2 + 1]) << 16);
      *(unsigned int*)&hlds[col][wv * 16 + lg * 4 + rp * 2] = pr;
    }
  }
  __syncthreads();
  #pragma unroll
  for (int pass = 0; pass < 6; ++pass) {
    const int col = pass * 32 + (t >> 3);
    const int r8 = (t & 7) * 8;
    *(uint4*)&h_t[(((size_t)(gb * HC + col)) << 10) + nl0 + r8] =
        *(const uint4*)&hlds[col][r8];
  }
}

// ---------------------------------------------------------------------------
// k_att: fused 3-layer GAT attention + MFMA PV + ones-column denominator +
// relu + pool. Double-buffered prefetch PINNED with sched_barrier(0);
// XCD-chunked swizzle. grid = 1024 x 192 (3 waves, one per layer; wave owns
// 16 complete rows).
// ---------------------------------------------------------------------------
__global__ __launch_bounds__(192) void k_att(
    const unsigned char* __restrict__ msk8, const unsigned short* __restrict__ h_t,
    const float* __restrict__ f1, const float* __restrict__ f2,
    float* __restrict__ pooled)
{
  const int bid = blockIdx.x;
  const int blk = (bid & 7) * 128 + (bid >> 3);  // 8 XCDs x 128: 2 batches/XCD
  const int b = blk >> 6;
  const int i0 = (blk & 63) * 16;
  const int t = threadIdx.x;
  const int l = t >> 6, lane = t & 63;
  const int lr = lane & 15, lg = lane >> 4;

  __shared__ float uvt[NL][2][N];              // 24 KB u/v tables

  // prologue: layer-l tables + unmasked max (wave l handles layer l)
  const float* f2p = f2 + (size_t)l * (B * N) + b * N;
  const int jb = lane * 16;
  float fv[16];
  {
    const float4 c0 = *(const float4*)&f2p[jb];
    const float4 c1 = *(const float4*)&f2p[jb + 4];
    const float4 c2 = *(const float4*)&f2p[jb + 8];
    const float4 c3 = *(const float4*)&f2p[jb + 12];
    fv[0]=c0.x; fv[1]=c0.y; fv[2]=c0.z; fv[3]=c0.w;
    fv[4]=c1.x; fv[5]=c1.y; fv[6]=c1.z; fv[7]=c1.w;
    fv[8]=c2.x; fv[9]=c2.y; fv[10]=c2.z; fv[11]=c2.w;
    fv[12]=c3.x; fv[13]=c3.y; fv[14]=c3.z; fv[15]=c3.w;
  }
  float mx = fv[0];
  #pragma unroll
  for (int e = 1; e < 16; ++e) mx = fmaxf(mx, fv[e]);
  #pragma unroll
  for (int off = 1; off < 64; off <<= 1) mx = fmaxf(mx, __shfl_xor(mx, off));

  {
    float ue[16], ve[16];
    #pragma unroll
    for (int e = 0; e < 16; ++e) {
      ue[e] = exp2f(fv[e]);
      ve[e] = exp2f(0.2f * fv[e]);
    }
    #pragma unroll
    for (int q = 0; q < 4; ++q) {
      *(float4*)&uvt[l][0][jb + q * 4] = (float4){ue[q*4], ue[q*4+1], ue[q*4+2], ue[q*4+3]};
      *(float4*)&uvt[l][1][jb + q * 4] = (float4){ve[q*4], ve[q*4+1], ve[q*4+2], ve[q*4+3]};
    }
  }
  __syncthreads();

  const float f1r = f1[(size_t)l * (B * N) + b * N + i0 + lr];
  const float tts = f1r + mx;
  const float sr = fmaxf(tts, 0.f) + 0.2f * fminf(tts, 0.f);  // valid upper bound
  const float A = exp2f(f1r - sr);
  const float C = exp2f(0.2f * f1r - sr);
  const float T = exp2f(-f1r);                 // u_j > T  <=>  f1+f2 > 0

  const unsigned char* mrow = msk8 + ((size_t)(b * N + i0 + lr) << 7);
  const unsigned short* hb = h_t + (((size_t)(b * HC + l * 64)) << 10);
  const int klane = lg * 8;
  const float* ut = &uvt[l][0][0];
  const float* vt = &uvt[l][1][0];
  const bf16x8 ones = {(short)0x3F80, (short)0x3F80, (short)0x3F80, (short)0x3F80,
                       (short)0x3F80, (short)0x3F80, (short)0x3F80, (short)0x3F80};

  f32x4 acc[4];
  #pragma unroll
  for (int n = 0; n < 4; ++n) acc[n] = (f32x4){0.f, 0.f, 0.f, 0.f};
  f32x4 accd = (f32x4){0.f, 0.f, 0.f, 0.f};

#define LOADJ(BUF, MW, J) {                                                   \
    const int jj = (J) & (N - 1);                                             \
    MW = *(const unsigned long long*)&mrow[jj >> 3];                          \
    _Pragma("unroll")                                                         \
    for (int q = 0; q < 8; ++q) {                                             \
      const int ks = q >> 2, n = q & 3;                                       \
      BUF[q] = *(const bf16x8*)&hb[(((size_t)(n * 16 + lr)) << 10) + jj +     \
                                   ks * 32 + klane];                          \
    } }

#define COMPJ(BUF, MW, J) {                                                   \
    _Pragma("unroll")                                                         \
    for (int ks = 0; ks < 2; ++ks) {                                          \
      const int kb = (J) + ks * 32 + klane;                                   \
      const float4 u0 = *(const float4*)&ut[kb];                              \
      const float4 u1 = *(const float4*)&ut[kb + 4];                          \
      const float4 v0 = *(const float4*)&vt[kb];                              \
      const float4 v1 = *(const float4*)&vt[kb + 4];                          \
      const float uu[8] = {u0.x, u0.y, u0.z, u0.w, u1.x, u1.y, u1.z, u1.w};   \
      const float vv[8] = {v0.x, v0.y, v0.z, v0.w, v1.x, v1.y, v1.z, v1.w};   \
      const unsigned int wb = (unsigned int)((MW) >> (ks * 32 + klane));      \
      unsigned int pk[4];                                                     \
      _Pragma("unroll")                                                       \
      for (int ep = 0; ep < 4; ++ep) {                                        \
        unsigned int pr[2];                                                   \
        _Pragma("unroll")                                                     \
        for (int h = 0; h < 2; ++h) {                                         \
          const int e = ep * 2 + h;                                           \
          const bool pos = uu[e] > T;                                         \
          const float z = pos ? uu[e] : vv[e];                                \
          const float wgt = pos ? A : C;                                      \
          float p = wgt * z;                                                  \
          p = ((wb >> e) & 1u) ? p : 0.f;                                     \
          pr[h] = __builtin_bit_cast(unsigned int, p) + 0x8000u;              \
        }                                                                     \
        pk[ep] = __builtin_amdgcn_perm(pr[1], pr[0], 0x07060302u);            \
      }                                                                       \
      const u32x4 pkv = {pk[0], pk[1], pk[2], pk[3]};                         \
      const bf16x8 av = __builtin_bit_cast(bf16x8, pkv);                      \
      _Pragma("unroll")                                                       \
      for (int n = 0; n < 4; ++n)                                             \
        acc[n] = __builtin_amdgcn_mfma_f32_16x16x32_bf16(av, BUF[ks * 4 + n], \
                                                         acc[n], 0, 0, 0);    \
      accd = __builtin_amdgcn_mfma_f32_16x16x32_bf16(av, ones, accd, 0, 0, 0);\
    } }

  bf16x8 bA[8], bB[8];
  unsigned long long mwA, mwB;
  LOADJ(bA, mwA, 0);
  __builtin_amdgcn_sched_barrier(0);
  for (int j0 = 0; j0 < N; j0 += 128) {
    LOADJ(bB, mwB, j0 + 64);                   // issue next-tile loads ...
    __builtin_amdgcn_sched_barrier(0);         // ... and PIN them here
    COMPJ(bA, mwA, j0);                        // compute current (already in regs)
    __builtin_amdgcn_sched_barrier(0);
    LOADJ(bA, mwA, j0 + 128);                  // wraps harmlessly on last iter
    __builtin_amdgcn_sched_barrier(0);
    COMPJ(bB, mwB, j0 + 64);
    __builtin_amdgcn_sched_barrier(0);
  }
#undef LOADJ
#undef COMPJ

  // epilogue: rows lg*4+r owned by this lane's acc regs; denom from accd
  float dn[4];
  #pragma unroll
  for (int r = 0; r < 4; ++r) dn[r] = 1.f / fmaxf(accd[r], 1e-37f);

  #pragma unroll
  for (int n = 0; n < 4; ++n) {
    float csum = 0.f;
    #pragma unroll
    for (int r = 0; r < 4; ++r) csum += fmaxf(acc[n][r] * dn[r], 0.f);
    csum += __shfl_xor(csum, 16);
    csum += __shfl_xor(csum, 32);
    if (lg == 0) atomicAdd(&pooled[b * HC + l * 64 + n * 16 + lr], csum);
  }
}

// ---------------------------------------------------------------------------
// k_head: mean + FC1(relu) + FC2 + softmax.  grid = B.
// ---------------------------------------------------------------------------
__global__ __launch_bounds__(192) void k_head(
    const float* __restrict__ pooled_sums, const float* __restrict__ W1,
    const float* __restrict__ b1, const float* __restrict__ W2,
    const float* __restrict__ b2, float* __restrict__ out)
{
  const int b = blockIdx.x, t = threadIdx.x;
  __shared__ float pooled[HC];
  __shared__ float z[FCH];
  __shared__ float logits[NC];

  if (t < HC) pooled[t] = pooled_sums[b * HC + t] * (1.f / (float)N);
  __syncthreads();

  if (t < FCH) {
    float a = b1[t];
    #pragma unroll 4
    for (int f = 0; f < HC; ++f) a += pooled[f] * W1[(size_t)f * FCH + t];
    z[t] = a > 0.f ? a : 0.f;
  }
  __syncthreads();

  if (t < NC) {
    float a = b2[t];
    #pragma unroll 4
    for (int f = 0; f < FCH; ++f) a += z[f] * W2[(size_t)f * NC + t];
    logits[t] = a;
  }
  __syncthreads();

  if (t == 0) {
    float mxl = logits[0];
    for (int c = 1; c < NC; ++c) mxl = fmaxf(mxl, logits[c]);
    float e[NC], sum = 0.f;
    for (int c = 0; c < NC; ++c) { e[c] = __expf(logits[c] - mxl); sum += e[c]; }
    const float inv = 1.f / sum;
    for (int c = 0; c < NC; ++c) out[b * NC + c] = e[c] * inv;
  }
}

// ---------------------------------------------------------------------------
extern "C" void kernel_launch(void* const* d_in, const int* in_sizes, int n_in,
                              void* d_out, int out_size, void* d_ws, size_t ws_size,
                              hipStream_t stream)
{
  const float* x   = (const float*)d_in[0];
  const float* adj = (const float*)d_in[1];
  const float* Ws  = (const float*)d_in[2];
  const float* a1  = (const float*)d_in[3];
  const float* a2  = (const float*)d_in[4];
  const float* W1  = (const float*)d_in[5];
  const float* b1  = (const float*)d_in[6];
  const float* W2  = (const float*)d_in[7];
  const float* b2  = (const float*)d_in[8];
  float* out = (float*)d_out;

  // workspace layout (16B aligned chunks)
  unsigned short* h_t   = (unsigned short*)d_ws;                       // 6.29 MB
  float*          f1    = (float*)(h_t + (size_t)B * HC * N);          // 196 KB
  float*          f2    = f1 + (size_t)NL * B * N;                     // 196 KB
  float*          pooled= f2 + (size_t)NL * B * N;                     // 12 KB
  unsigned short* wt_hi = (unsigned short*)(pooled + B * HC + 16);     // 48 KB
  unsigned short* wt_lo = wt_hi + (size_t)HC * NF;                     // 48 KB
  unsigned short* msk   = wt_lo + (size_t)HC * NF;                     // 2 MB

  k_wt  <<<96,  256, 0, stream>>>(Ws, wt_hi, wt_lo, pooled);
  k_fm  <<<768, 256, 0, stream>>>(x, adj, wt_hi, wt_lo, a1, a2, h_t, f1, f2, msk);
  k_att <<<1024, 192, 0, stream>>>((const unsigned char*)msk, h_t, f1, f2, pooled);
  k_head<<<B, 192, 0, stream>>>(pooled, W1, b1, W2, b2, out);
}

// Round 8
// 101.070 us; speedup vs baseline: 1.2806x; 1.0882x over previous
//
#include <hip/hip_runtime.h>

#define B 16
#define N 1024
#define NF 128
#define NL 3
#define AH 64
#define HC 192   // NL*AH
#define FCH 128
#define NC 10
#define L2E 1.44269504088896f

typedef __attribute__((ext_vector_type(8))) short bf16x8;
typedef __attribute__((ext_vector_type(4))) float f32x4;
typedef __attribute__((ext_vector_type(4))) unsigned int u32x4;

static __device__ __forceinline__ unsigned short f2bf(float f) {
  unsigned int x = __builtin_bit_cast(unsigned int, f);
  return (unsigned short)((x + 0x7fffu + ((x >> 16) & 1u)) >> 16);   // RNE
}
static __device__ __forceinline__ float bf2f(unsigned short u) {
  unsigned int x = ((unsigned int)u) << 16;
  return __builtin_bit_cast(float, x);
}

// ---------------------------------------------------------------------------
// k_wt: Ws -> bf16 hi/lo in MFMA-FRAGMENT order:
//   idx = ((n*4+kf)*64+lane)*8+e ; col=n*16+(lane&15) ; k=kf*32+(lane>>4)*8+e
// Also zeroes pooled. grid = 96 x 256.
// ---------------------------------------------------------------------------
__global__ __launch_bounds__(256) void k_wt(
    const float* __restrict__ Ws, unsigned short* __restrict__ wt_hi,
    unsigned short* __restrict__ wt_lo, float* __restrict__ pooled)
{
  const int idx = blockIdx.x * 256 + threadIdx.x;     // 0..24575
  const int n = idx >> 11;
  const int kf = (idx >> 9) & 3;
  const int lane = (idx >> 3) & 63;
  const int e = idx & 7;
  const int col = n * 16 + (lane & 15);
  const int k = kf * 32 + (lane >> 4) * 8 + e;
  const float w = Ws[(size_t)((col >> 6) * NF + k) * AH + (col & 63)];
  const unsigned short hi = f2bf(w);
  wt_hi[idx] = hi;
  wt_lo[idx] = f2bf(w - bf2f(hi));
  if (idx < B * HC) pooled[idx] = 0.f;
}

// ---------------------------------------------------------------------------
// k_fm: bid%3==0 -> feat (64 nodes, split-bf16 MFMA; outputs h in FRAGMENT
// order h_f + f1/f2 f32 pre-scaled by log2e); else -> adj mask in FRAGMENT
// order mskf (u16 per lane per 64-j tile) via ballot + LDS transpose.
// grid = 768 x 256.
// ---------------------------------------------------------------------------
__global__ __launch_bounds__(256) void k_fm(
    const float* __restrict__ x, const float* __restrict__ adj,
    const unsigned short* __restrict__ wt_hi, const unsigned short* __restrict__ wt_lo,
    const float* __restrict__ a1, const float* __restrict__ a2,
    unsigned short* __restrict__ h_f, float* __restrict__ f1g,
    float* __restrict__ f2g, unsigned short* __restrict__ mskf)
{
  const int bid = blockIdx.x, t = threadIdx.x;

  __shared__ unsigned long long stage[32][17];   // mask transpose (4.4KB)
  __shared__ unsigned short hlds[HC][72];        // feat transpose (27.6KB)

  if (bid % 3 != 0) {                     // ---- mask role: 32 adj rows ----
    const int mid = bid - bid / 3 - 1;    // 0..511
    const int wv = t >> 6, lane = t & 63;
    const int r0 = mid * 32;
    #pragma unroll 2
    for (int rr = 0; rr < 8; ++rr) {
      const int rowl = wv * 8 + rr;
      const float* ap = adj + ((size_t)(r0 + rowl) << 10);
      #pragma unroll
      for (int cq = 0; cq < 16; ++cq) {
        const float v = ap[cq * 64 + lane];           // coalesced 256B
        const unsigned long long w = __ballot(v != 0.f);  // bit l <-> j=cq*64+l
        if (lane == 0) stage[rowl][cq] = w;
      }
    }
    __syncthreads();
    // transpose to fragment order: u16(lane) bits e of byte ks =
    // adj[row=iblk*16+(lane&15)][jt*64 + ks*32 + (lane>>4)*8 + e]
    const int b_ = r0 >> 10, iblk0 = (r0 & 1023) >> 4;
    const unsigned char* stb = (const unsigned char*)stage;
    #pragma unroll
    for (int u = 0; u < 8; ++u) {
      const int o = u * 256 + t;
      const int lane_o = o & 63, jt_o = (o >> 6) & 15, ib_o = o >> 10;
      const int rowl = ib_o * 16 + (lane_o & 15), lg_o = lane_o >> 4;
      const unsigned int b0 = stb[(rowl * 17 + jt_o) * 8 + lg_o];
      const unsigned int b1 = stb[(rowl * 17 + jt_o) * 8 + 4 + lg_o];
      mskf[((size_t)((b_ * 64 + iblk0 + ib_o) * 16 + jt_o)) * 64 + lane_o] =
          (unsigned short)(b0 | (b1 << 8));
    }
    return;
  }

  // ---- feat role: nodes n0g..n0g+63 ----
  const int fid = bid / 3;
  const int n0g = fid * 64;
  const int gb = n0g >> 10, nl0 = n0g & 1023;
  const int wv = t >> 6, lane = t & 63;
  const int lr = lane & 15, lg = lane >> 4;
  const int row = n0g + wv * 16 + lr;

  // whole x row (128 floats) -> split bf16, kept in registers
  bf16x8 xhi[4], xlo[4];
  #pragma unroll
  for (int kf = 0; kf < 4; ++kf) {
    const float4 q0 = *(const float4*)&x[(size_t)row * NF + kf * 32 + lg * 8];
    const float4 q1 = *(const float4*)&x[(size_t)row * NF + kf * 32 + lg * 8 + 4];
    const float xv[8] = {q0.x, q0.y, q0.z, q0.w, q1.x, q1.y, q1.z, q1.w};
    #pragma unroll
    for (int e = 0; e < 8; ++e) {
      const unsigned short hi = f2bf(xv[e]);
      xhi[kf][e] = (short)hi;
      xlo[kf][e] = (short)f2bf(xv[e] - bf2f(hi));
    }
  }

  f32x4 acc[12];
  #pragma unroll
  for (int n = 0; n < 12; ++n) acc[n] = (f32x4){0.f, 0.f, 0.f, 0.f};

  #pragma unroll
  for (int n = 0; n < 12; ++n) {
    #pragma unroll
    for (int kf = 0; kf < 4; ++kf) {
      const int fo = ((n * 4 + kf) << 9) + lane * 8;
      const bf16x8 whi = *(const bf16x8*)&wt_hi[fo];
      const bf16x8 wlo = *(const bf16x8*)&wt_lo[fo];
      acc[n] = __builtin_amdgcn_mfma_f32_16x16x32_bf16(xhi[kf], whi, acc[n], 0, 0, 0);
      acc[n] = __builtin_amdgcn_mfma_f32_16x16x32_bf16(xhi[kf], wlo, acc[n], 0, 0, 0);
      acc[n] = __builtin_amdgcn_mfma_f32_16x16x32_bf16(xlo[kf], whi, acc[n], 0, 0, 0);
    }
  }

  // f1/f2 (exact f32), pre-scaled by log2e
  float s1[3][4], s2[3][4];
  #pragma unroll
  for (int l = 0; l < 3; ++l)
    #pragma unroll
    for (int r = 0; r < 4; ++r) { s1[l][r] = 0.f; s2[l][r] = 0.f; }
  #pragma unroll
  for (int n = 0; n < 12; ++n) {
    const int col = n * 16 + lr;
    const float a1v = a1[col] * L2E, a2v = a2[col] * L2E;
    const int l = n >> 2;
    #pragma unroll
    for (int r = 0; r < 4; ++r) {
      s1[l][r] += acc[n][r] * a1v;
      s2[l][r] += acc[n][r] * a2v;
    }
  }
  #pragma unroll
  for (int off = 1; off < 16; off <<= 1)
    #pragma unroll
    for (int l = 0; l < 3; ++l)
      #pragma unroll
      for (int r = 0; r < 4; ++r) {
        s1[l][r] += __shfl_xor(s1[l][r], off);
        s2[l][r] += __shfl_xor(s2[l][r], off);
      }
  if (lr == 0) {
    #pragma unroll
    for (int l = 0; l < 3; ++l)
      #pragma unroll
      for (int r = 0; r < 4; ++r) {
        const int rw = n0g + wv * 16 + lg * 4 + r;
        f1g[(size_t)l * (B * N) + rw] = s1[l][r];
        f2g[(size_t)l * (B * N) + rw] = s2[l][r];
      }
  }

  // pack bf16 -> LDS transpose (node-local index = wv*16+lg*4+r)
  #pragma unroll
  for (int n = 0; n < 12; ++n) {
    const int col = n * 16 + lr;
    #pragma unroll
    for (int rp = 0; rp < 2; ++rp) {
      const unsigned int pr = (unsigned int)f2bf(acc[n][rp * 2]) |
                              ((unsigned int)f2bf(acc[n][rp * 2 + 1]) << 16);
      *(unsigned int*)&hlds[col][wv * 16 + lg * 4 + rp * 2] = pr;
    }
  }
  __syncthreads();
  // fragment-order store: element (b,l,n,jb,lane,e) = h[col=l*64+n*16+(lane&15)]
  //                                                    [j = jb*32+(lane>>4)*8+e]
  #pragma unroll
  for (int p = 0; p < 6; ++p) {
    const int widx = p * 256 + t;                  // 0..1535
    const int lane_w = widx & 63;
    const int jb2 = (widx >> 6) & 1;
    const int n_w = (widx >> 7) & 3;
    const int l_w = widx >> 9;
    const int col = l_w * 64 + n_w * 16 + (lane_w & 15);
    const int jloc = jb2 * 32 + (lane_w >> 4) * 8;
    const size_t off =
        ((((size_t)(gb * 3 + l_w) * 4 + n_w) * 32 + (nl0 >> 5) + jb2) * 64 + lane_w) * 8;
    *(uint4*)&h_f[off] = *(const uint4*)&hlds[col][jloc];
  }
}

// ---------------------------------------------------------------------------
// k_att: fused 3-layer GAT attention + MFMA PV + ones-column denominator +
// relu + pool. ALL j-loop loads coalesced (fragment-order h_f + mskf);
// double-buffered, sched_barrier-pinned. grid = 1024 x 192 (3 waves, one
// per layer; wave owns 16 complete rows).
// ---------------------------------------------------------------------------
__global__ __launch_bounds__(192) void k_att(
    const unsigned short* __restrict__ mskf, const unsigned short* __restrict__ h_f,
    const float* __restrict__ f1, const float* __restrict__ f2,
    float* __restrict__ pooled)
{
  const int bid = blockIdx.x;
  const int blk = (bid & 7) * 128 + (bid >> 3);  // 8 XCDs x 128: 2 batches/XCD
  const int b = blk >> 6;
  const int i0 = (blk & 63) * 16;
  const int t = threadIdx.x;
  const int l = t >> 6, lane = t & 63;
  const int lr = lane & 15, lg = lane >> 4;

  __shared__ float uvt[NL][2][N];              // 24 KB u/v tables

  // prologue: layer-l tables + unmasked max (coalesced: lane*4 chunks)
  const float* f2p = f2 + (size_t)l * (B * N) + b * N;
  float mx = -1e30f;
  #pragma unroll
  for (int ch = 0; ch < 4; ++ch) {
    const int jb = ch * 256 + lane * 4;
    const float4 q = *(const float4*)&f2p[jb];
    *(float4*)&uvt[l][0][jb] =
        (float4){exp2f(q.x), exp2f(q.y), exp2f(q.z), exp2f(q.w)};
    *(float4*)&uvt[l][1][jb] =
        (float4){exp2f(0.2f * q.x), exp2f(0.2f * q.y), exp2f(0.2f * q.z), exp2f(0.2f * q.w)};
    mx = fmaxf(mx, fmaxf(fmaxf(q.x, q.y), fmaxf(q.z, q.w)));
  }
  #pragma unroll
  for (int off = 1; off < 64; off <<= 1) mx = fmaxf(mx, __shfl_xor(mx, off));
  __syncthreads();

  const float f1r = f1[(size_t)l * (B * N) + b * N + i0 + lr];
  const float tts = f1r + mx;
  const float sr = fmaxf(tts, 0.f) + 0.2f * fminf(tts, 0.f);  // valid upper bound
  const float A = exp2f(f1r - sr);
  const float C = exp2f(0.2f * f1r - sr);
  const float T = exp2f(-f1r);                 // u_j > T  <=>  f1+f2 > 0

  const unsigned short* hfb = h_f + ((size_t)(b * 3 + l)) * 65536;  // 4*32*64*8
  const unsigned short* mkb = mskf + ((size_t)(b * 64 + (i0 >> 4))) * 16 * 64;
  const float* ut = &uvt[l][0][0];
  const float* vt = &uvt[l][1][0];
  const bf16x8 ones = {(short)0x3F80, (short)0x3F80, (short)0x3F80, (short)0x3F80,
                       (short)0x3F80, (short)0x3F80, (short)0x3F80, (short)0x3F80};

  f32x4 acc[4];
  #pragma unroll
  for (int n = 0; n < 4; ++n) acc[n] = (f32x4){0.f, 0.f, 0.f, 0.f};
  f32x4 accd = (f32x4){0.f, 0.f, 0.f, 0.f};

#define LOADJ(BUF, MW, J) {                                                   \
    const int jj = (J) & (N - 1);                                             \
    MW = mkb[(jj >> 6) * 64 + lane];                                          \
    _Pragma("unroll")                                                         \
    for (int q = 0; q < 8; ++q) {                                             \
      const int ks = q >> 2, n = q & 3;                                       \
      BUF[q] = *(const bf16x8*)&hfb[(((size_t)n * 32 + (jj >> 5) + ks) * 64 + \
                                     lane) * 8];                              \
    } }

#define COMPJ(BUF, MW, J) {                                                   \
    _Pragma("unroll")                                                         \
    for (int ks = 0; ks < 2; ++ks) {                                          \
      const int kb = (J) + ks * 32 + lg * 8;                                  \
      const float4 u0 = *(const float4*)&ut[kb];                              \
      const float4 u1 = *(const float4*)&ut[kb + 4];                          \
      const float4 v0 = *(const float4*)&vt[kb];                              \
      const float4 v1 = *(const float4*)&vt[kb + 4];                          \
      const float uu[8] = {u0.x, u0.y, u0.z, u0.w, u1.x, u1.y, u1.z, u1.w};   \
      const float vv[8] = {v0.x, v0.y, v0.z, v0.w, v1.x, v1.y, v1.z, v1.w};   \
      const unsigned int wb = ((unsigned int)(MW) >> (ks * 8)) & 0xffu;       \
      unsigned int pk[4];                                                     \
      _Pragma("unroll")                                                       \
      for (int ep = 0; ep < 4; ++ep) {                                        \
        unsigned int pr[2];                                                   \
        _Pragma("unroll")                                                     \
        for (int h = 0; h < 2; ++h) {                                         \
          const int e = ep * 2 + h;                                           \
          const bool pos = uu[e] > T;                                         \
          const float z = pos ? uu[e] : vv[e];                                \
          const float wgt = pos ? A : C;                                      \
          float p = wgt * z;                                                  \
          p = ((wb >> e) & 1u) ? p : 0.f;                                     \
          pr[h] = __builtin_bit_cast(unsigned int, p) + 0x8000u;              \
        }                                                                     \
        pk[ep] = __builtin_amdgcn_perm(pr[1], pr[0], 0x07060302u);            \
      }                                                                       \
      const u32x4 pkv = {pk[0], pk[1], pk[2], pk[3]};                         \
      const bf16x8 av = __builtin_bit_cast(bf16x8, pkv);                      \
      _Pragma("unroll")                                                       \
      for (int n = 0; n < 4; ++n)                                             \
        acc[n] = __builtin_amdgcn_mfma_f32_16x16x32_bf16(av, BUF[ks * 4 + n], \
                                                         acc[n], 0, 0, 0);    \
      accd = __builtin_amdgcn_mfma_f32_16x16x32_bf16(av, ones, accd, 0, 0, 0);\
    } }

  bf16x8 bA[8], bB[8];
  unsigned short mwA, mwB;
  LOADJ(bA, mwA, 0);
  __builtin_amdgcn_sched_barrier(0);
  for (int j0 = 0; j0 < N; j0 += 128) {
    LOADJ(bB, mwB, j0 + 64);                   // issue next-tile loads ...
    __builtin_amdgcn_sched_barrier(0);         // ... and PIN them here
    COMPJ(bA, mwA, j0);                        // compute current (in regs)
    __builtin_amdgcn_sched_barrier(0);
    LOADJ(bA, mwA, j0 + 128);                  // wraps harmlessly on last iter
    __builtin_amdgcn_sched_barrier(0);
    COMPJ(bB, mwB, j0 + 64);
    __builtin_amdgcn_sched_barrier(0);
  }
#undef LOADJ
#undef COMPJ

  // epilogue: rows lg*4+r owned by this lane's acc regs; denom from accd
  float dn[4];
  #pragma unroll
  for (int r = 0; r < 4; ++r) dn[r] = 1.f / fmaxf(accd[r], 1e-37f);

  #pragma unroll
  for (int n = 0; n < 4; ++n) {
    float csum = 0.f;
    #pragma unroll
    for (int r = 0; r < 4; ++r) csum += fmaxf(acc[n][r] * dn[r], 0.f);
    csum += __shfl_xor(csum, 16);
    csum += __shfl_xor(csum, 32);
    if (lg == 0) atomicAdd(&pooled[b * HC + l * 64 + n * 16 + lr], csum);
  }
}

// ---------------------------------------------------------------------------
// k_head: mean + FC1(relu) + FC2 + softmax.  grid = B.
// ---------------------------------------------------------------------------
__global__ __launch_bounds__(192) void k_head(
    const float* __restrict__ pooled_sums, const float* __restrict__ W1,
    const float* __restrict__ b1, const float* __restrict__ W2,
    const float* __restrict__ b2, float* __restrict__ out)
{
  const int b = blockIdx.x, t = threadIdx.x;
  __shared__ float pooled[HC];
  __shared__ float z[FCH];
  __shared__ float logits[NC];

  if (t < HC) pooled[t] = pooled_sums[b * HC + t] * (1.f / (float)N);
  __syncthreads();

  if (t < FCH) {
    float a = b1[t];
    #pragma unroll 4
    for (int f = 0; f < HC; ++f) a += pooled[f] * W1[(size_t)f * FCH + t];
    z[t] = a > 0.f ? a : 0.f;
  }
  __syncthreads();

  if (t < NC) {
    float a = b2[t];
    #pragma unroll 4
    for (int f = 0; f < FCH; ++f) a += z[f] * W2[(size_t)f * NC + t];
    logits[t] = a;
  }
  __syncthreads();

  if (t == 0) {
    float mxl = logits[0];
    for (int c = 1; c < NC; ++c) mxl = fmaxf(mxl, logits[c]);
    float e[NC], sum = 0.f;
    for (int c = 0; c < NC; ++c) { e[c] = __expf(logits[c] - mxl); sum += e[c]; }
    const float inv = 1.f / sum;
    for (int c = 0; c < NC; ++c) out[b * NC + c] = e[c] * inv;
  }
}

// ---------------------------------------------------------------------------
extern "C" void kernel_launch(void* const* d_in, const int* in_sizes, int n_in,
                              void* d_out, int out_size, void* d_ws, size_t ws_size,
                              hipStream_t stream)
{
  const float* x   = (const float*)d_in[0];
  const float* adj = (const float*)d_in[1];
  const float* Ws  = (const float*)d_in[2];
  const float* a1  = (const float*)d_in[3];
  const float* a2  = (const float*)d_in[4];
  const float* W1  = (const float*)d_in[5];
  const float* b1  = (const float*)d_in[6];
  const float* W2  = (const float*)d_in[7];
  const float* b2  = (const float*)d_in[8];
  float* out = (float*)d_out;

  // workspace layout (16B aligned chunks)
  unsigned short* h_f   = (unsigned short*)d_ws;                       // 6.29 MB
  float*          f1    = (float*)(h_f + (size_t)B * HC * N);          // 196 KB
  float*          f2    = f1 + (size_t)NL * B * N;                     // 196 KB
  float*          pooled= f2 + (size_t)NL * B * N;                     // 12 KB
  unsigned short* wt_hi = (unsigned short*)(pooled + B * HC + 16);     // 48 KB
  unsigned short* wt_lo = wt_hi + (size_t)HC * NF;                     // 48 KB
  unsigned short* mskf  = wt_lo + (size_t)HC * NF;                     // 2 MB

  k_wt  <<<96,  256, 0, stream>>>(Ws, wt_hi, wt_lo, pooled);
  k_fm  <<<768, 256, 0, stream>>>(x, adj, wt_hi, wt_lo, a1, a2, h_f, f1, f2, mskf);
  k_att <<<1024, 192, 0, stream>>>(mskf, h_f, f1, f2, pooled);
  k_head<<<B, 192, 0, stream>>>(pooled, W1, b1, W2, b2, out);
}

// Round 9
// 87.185 us; speedup vs baseline: 1.4846x; 1.1593x over previous
//
#include <hip/hip_runtime.h>

#define B 16
#define N 1024
#define NF 128
#define NL 3
#define AH 64
#define HC 192   // NL*AH
#define FCH 128
#define NC 10
#define L2E 1.44269504088896f
#define PAD 68   // adj tile row stride (floats): conflict-free ds_read_b128

typedef __attribute__((ext_vector_type(8))) short bf16x8;
typedef __attribute__((ext_vector_type(4))) float f32x4;
typedef __attribute__((ext_vector_type(4))) unsigned int u32x4;

static __device__ __forceinline__ unsigned short f2bf(float f) {
  unsigned int x = __builtin_bit_cast(unsigned int, f);
  return (unsigned short)((x + 0x7fffu + ((x >> 16) & 1u)) >> 16);   // RNE
}
static __device__ __forceinline__ float bf2f(unsigned short u) {
  unsigned int x = ((unsigned int)u) << 16;
  return __builtin_bit_cast(float, x);
}

// ---------------------------------------------------------------------------
// k_wt: Ws -> bf16 hi/lo in MFMA-FRAGMENT order:
//   idx = ((n*4+kf)*64+lane)*8+e ; col=n*16+(lane&15) ; k=kf*32+(lane>>4)*8+e
// Also zeroes pooled. grid = 96 x 256.
// ---------------------------------------------------------------------------
__global__ __launch_bounds__(256) void k_wt(
    const float* __restrict__ Ws, unsigned short* __restrict__ wt_hi,
    unsigned short* __restrict__ wt_lo, float* __restrict__ pooled)
{
  const int idx = blockIdx.x * 256 + threadIdx.x;     // 0..24575
  const int n = idx >> 11;
  const int kf = (idx >> 9) & 3;
  const int lane = (idx >> 3) & 63;
  const int e = idx & 7;
  const int col = n * 16 + (lane & 15);
  const int k = kf * 32 + (lane >> 4) * 8 + e;
  const float w = Ws[(size_t)((col >> 6) * NF + k) * AH + (col & 63)];
  const unsigned short hi = f2bf(w);
  wt_hi[idx] = hi;
  wt_lo[idx] = f2bf(w - bf2f(hi));
  if (idx < B * HC) pooled[idx] = 0.f;
}

// ---------------------------------------------------------------------------
// k_feat: 64 nodes/block, split-bf16 MFMA (x = xhi+xlo, W = whi+wlo);
// outputs h in FRAGMENT order h_f + f1/f2 f32 pre-scaled by log2e.
// grid = 256 x 256.
// ---------------------------------------------------------------------------
__global__ __launch_bounds__(256) void k_feat(
    const float* __restrict__ x,
    const unsigned short* __restrict__ wt_hi, const unsigned short* __restrict__ wt_lo,
    const float* __restrict__ a1, const float* __restrict__ a2,
    unsigned short* __restrict__ h_f, float* __restrict__ f1g,
    float* __restrict__ f2g)
{
  __shared__ unsigned short hlds[HC][72];        // transpose buffer (27.6KB)
  const int t = threadIdx.x;
  const int n0g = blockIdx.x * 64;
  const int gb = n0g >> 10, nl0 = n0g & 1023;
  const int wv = t >> 6, lane = t & 63;
  const int lr = lane & 15, lg = lane >> 4;
  const int row = n0g + wv * 16 + lr;

  // whole x row (128 floats) -> split bf16, kept in registers
  bf16x8 xhi[4], xlo[4];
  #pragma unroll
  for (int kf = 0; kf < 4; ++kf) {
    const float4 q0 = *(const float4*)&x[(size_t)row * NF + kf * 32 + lg * 8];
    const float4 q1 = *(const float4*)&x[(size_t)row * NF + kf * 32 + lg * 8 + 4];
    const float xv[8] = {q0.x, q0.y, q0.z, q0.w, q1.x, q1.y, q1.z, q1.w};
    #pragma unroll
    for (int e = 0; e < 8; ++e) {
      const unsigned short hi = f2bf(xv[e]);
      xhi[kf][e] = (short)hi;
      xlo[kf][e] = (short)f2bf(xv[e] - bf2f(hi));
    }
  }

  f32x4 acc[12];
  #pragma unroll
  for (int n = 0; n < 12; ++n) acc[n] = (f32x4){0.f, 0.f, 0.f, 0.f};

  #pragma unroll
  for (int n = 0; n < 12; ++n) {
    #pragma unroll
    for (int kf = 0; kf < 4; ++kf) {
      const int fo = ((n * 4 + kf) << 9) + lane * 8;
      const bf16x8 whi = *(const bf16x8*)&wt_hi[fo];
      const bf16x8 wlo = *(const bf16x8*)&wt_lo[fo];
      acc[n] = __builtin_amdgcn_mfma_f32_16x16x32_bf16(xhi[kf], whi, acc[n], 0, 0, 0);
      acc[n] = __builtin_amdgcn_mfma_f32_16x16x32_bf16(xhi[kf], wlo, acc[n], 0, 0, 0);
      acc[n] = __builtin_amdgcn_mfma_f32_16x16x32_bf16(xlo[kf], whi, acc[n], 0, 0, 0);
    }
  }

  // f1/f2 (exact f32), pre-scaled by log2e
  float s1[3][4], s2[3][4];
  #pragma unroll
  for (int l = 0; l < 3; ++l)
    #pragma unroll
    for (int r = 0; r < 4; ++r) { s1[l][r] = 0.f; s2[l][r] = 0.f; }
  #pragma unroll
  for (int n = 0; n < 12; ++n) {
    const int col = n * 16 + lr;
    const float a1v = a1[col] * L2E, a2v = a2[col] * L2E;
    const int l = n >> 2;
    #pragma unroll
    for (int r = 0; r < 4; ++r) {
      s1[l][r] += acc[n][r] * a1v;
      s2[l][r] += acc[n][r] * a2v;
    }
  }
  #pragma unroll
  for (int off = 1; off < 16; off <<= 1)
    #pragma unroll
    for (int l = 0; l < 3; ++l)
      #pragma unroll
      for (int r = 0; r < 4; ++r) {
        s1[l][r] += __shfl_xor(s1[l][r], off);
        s2[l][r] += __shfl_xor(s2[l][r], off);
      }
  if (lr == 0) {
    #pragma unroll
    for (int l = 0; l < 3; ++l)
      #pragma unroll
      for (int r = 0; r < 4; ++r) {
        const int rw = n0g + wv * 16 + lg * 4 + r;
        f1g[(size_t)l * (B * N) + rw] = s1[l][r];
        f2g[(size_t)l * (B * N) + rw] = s2[l][r];
      }
  }

  // pack bf16 -> LDS transpose (node-local index = wv*16+lg*4+r)
  #pragma unroll
  for (int n = 0; n < 12; ++n) {
    const int col = n * 16 + lr;
    #pragma unroll
    for (int rp = 0; rp < 2; ++rp) {
      const unsigned int pr = (unsigned int)f2bf(acc[n][rp * 2]) |
                              ((unsigned int)f2bf(acc[n][rp * 2 + 1]) << 16);
      *(unsigned int*)&hlds[col][wv * 16 + lg * 4 + rp * 2] = pr;
    }
  }
  __syncthreads();
  // fragment-order store: element (b,l,n,jslot,lane,e) = h[col=l*64+n*16+(lane&15)]
  //                                                       [j = jslot*32+(lane>>4)*8+e]
  #pragma unroll
  for (int p = 0; p < 6; ++p) {
    const int widx = p * 256 + t;                  // 0..1535
    const int lane_w = widx & 63;
    const int jb2 = (widx >> 6) & 1;
    const int n_w = (widx >> 7) & 3;
    const int l_w = widx >> 9;
    const int col = l_w * 64 + n_w * 16 + (lane_w & 15);
    const int jloc = jb2 * 32 + (lane_w >> 4) * 8;
    const size_t off =
        ((((size_t)(gb * 3 + l_w) * 4 + n_w) * 32 + (nl0 >> 5) + jb2) * 64 + lane_w) * 8;
    *(uint4*)&h_f[off] = *(const uint4*)&hlds[col][jloc];
  }
}

// ---------------------------------------------------------------------------
// k_att: fused 3-layer GAT attention + MFMA PV + ones-column denominator +
// relu + pool, with adj streamed DIRECTLY through a double-buffered LDS tile
// (no mask pre-pass). grid = 512 x 384 (6 waves = layer x rowgroup; wave owns
// 16 complete rows). XCD-chunked block swizzle.
// ---------------------------------------------------------------------------
__global__ __launch_bounds__(384) void k_att(
    const float* __restrict__ adj, const unsigned short* __restrict__ h_f,
    const float* __restrict__ f1, const float* __restrict__ f2,
    float* __restrict__ pooled)
{
  const int bid = blockIdx.x;
  const int blk = (bid & 7) * 64 + (bid >> 3);   // 8 XCDs x 64: 2 batches/XCD
  const int b = blk >> 5;
  const int i0 = (blk & 31) * 32;
  const int t = threadIdx.x;
  const int w = t >> 6, lane = t & 63;
  const int l = w >> 1, rg = w & 1;
  const int lr = lane & 15, lg = lane >> 4;

  __shared__ float uvt[NL][2][N];          // 24 KB u/v tables
  __shared__ float adjt[2][32][PAD];       // 17.4 KB double-buffered adj tile

  // ---- prologue: u/v tables (each (l,rg) wave writes half of layer l),
  //      full-N unmasked max per wave ----
  const float* f2p = f2 + (size_t)l * (B * N) + b * N;
  float mx = -1e30f;
  #pragma unroll
  for (int ch = 0; ch < 4; ++ch) {
    const int jb = ch * 256 + lane * 4;
    const float4 q = *(const float4*)&f2p[jb];
    mx = fmaxf(mx, fmaxf(fmaxf(q.x, q.y), fmaxf(q.z, q.w)));
    if ((ch >> 1) == rg) {
      *(float4*)&uvt[l][0][jb] =
          (float4){exp2f(q.x), exp2f(q.y), exp2f(q.z), exp2f(q.w)};
      *(float4*)&uvt[l][1][jb] =
          (float4){exp2f(0.2f * q.x), exp2f(0.2f * q.y), exp2f(0.2f * q.z), exp2f(0.2f * q.w)};
    }
  }
  #pragma unroll
  for (int off = 1; off < 64; off <<= 1) mx = fmaxf(mx, __shfl_xor(mx, off));

  const float f1r = f1[(size_t)l * (B * N) + b * N + i0 + rg * 16 + lr];
  const float tts = f1r + mx;
  const float sr = fmaxf(tts, 0.f) + 0.2f * fminf(tts, 0.f);  // valid upper bound
  const float A = exp2f(f1r - sr);
  const float C = exp2f(0.2f * f1r - sr);
  const float T = exp2f(-f1r);                 // u_j > T  <=>  f1+f2 > 0

  const float* adjb = adj + ((size_t)(b * N + i0)) * N;   // 32 rows x N
  const unsigned short* hfb = h_f + ((size_t)(b * 3 + l)) * 65536;
  const float* ut = &uvt[l][0][0];
  const float* vt = &uvt[l][1][0];
  const bf16x8 ones = {(short)0x3F80, (short)0x3F80, (short)0x3F80, (short)0x3F80,
                       (short)0x3F80, (short)0x3F80, (short)0x3F80, (short)0x3F80};

  // staging coords: flat q in [0,512): row=q>>4, c4=q&15; thread t does q=t
  // and (t<128) q=t+384
  const int sr0 = t >> 4, sc0 = (t & 15) * 4;
  const int sr1 = (t + 384) >> 4, sc1 = ((t + 384) & 15) * 4;

  // stage tile 0
  {
    const float4 s0 = *(const float4*)&adjb[(size_t)sr0 * N + sc0];
    float4 s1;
    if (t < 128) s1 = *(const float4*)&adjb[(size_t)sr1 * N + sc1];
    *(float4*)&adjt[0][sr0][sc0] = s0;
    if (t < 128) *(float4*)&adjt[0][sr1][sc1] = s1;
  }

  f32x4 acc[4];
  #pragma unroll
  for (int n = 0; n < 4; ++n) acc[n] = (f32x4){0.f, 0.f, 0.f, 0.f};
  f32x4 accd = (f32x4){0.f, 0.f, 0.f, 0.f};

#define LOADJ(BUF, J) {                                                       \
    const int jj = (J) & (N - 1);                                             \
    _Pragma("unroll")                                                         \
    for (int q = 0; q < 8; ++q) {                                             \
      const int ks = q >> 2, n = q & 3;                                       \
      BUF[q] = *(const bf16x8*)&hfb[(((size_t)n * 32 + (jj >> 5) + ks) * 64 + \
                                     lane) * 8];                              \
    } }

#define COMPJ(BUF, SB, J) {                                                   \
    _Pragma("unroll")                                                         \
    for (int ks = 0; ks < 2; ++ks) {                                          \
      const int kb = (J) + ks * 32 + lg * 8;                                  \
      const float4 u0 = *(const float4*)&ut[kb];                              \
      const float4 u1 = *(const float4*)&ut[kb + 4];                          \
      const float4 v0 = *(const float4*)&vt[kb];                              \
      const float4 v1 = *(const float4*)&vt[kb + 4];                          \
      const float4 m0 = *(const float4*)&adjt[SB][rg * 16 + lr][ks * 32 + lg * 8];     \
      const float4 m1 = *(const float4*)&adjt[SB][rg * 16 + lr][ks * 32 + lg * 8 + 4]; \
      const float uu[8] = {u0.x, u0.y, u0.z, u0.w, u1.x, u1.y, u1.z, u1.w};   \
      const float vv[8] = {v0.x, v0.y, v0.z, v0.w, v1.x, v1.y, v1.z, v1.w};   \
      const float mm[8] = {m0.x, m0.y, m0.z, m0.w, m1.x, m1.y, m1.z, m1.w};   \
      unsigned int pk[4];                                                     \
      _Pragma("unroll")                                                       \
      for (int ep = 0; ep < 4; ++ep) {                                        \
        unsigned int pr[2];                                                   \
        _Pragma("unroll")                                                     \
        for (int h = 0; h < 2; ++h) {                                         \
          const int e = ep * 2 + h;                                           \
          const bool pos = uu[e] > T;                                         \
          const float z = pos ? uu[e] : vv[e];                                \
          const float wgt = pos ? A : C;                                      \
          const float p = wgt * z * mm[e];        /* adj is exactly 0 or 1 */ \
          pr[h] = __builtin_bit_cast(unsigned int, p) + 0x8000u;              \
        }                                                                     \
        pk[ep] = __builtin_amdgcn_perm(pr[1], pr[0], 0x07060302u);            \
      }                                                                       \
      const u32x4 pkv = {pk[0], pk[1], pk[2], pk[3]};                         \
      const bf16x8 av = __builtin_bit_cast(bf16x8, pkv);                      \
      _Pragma("unroll")                                                       \
      for (int n = 0; n < 4; ++n)                                             \
        acc[n] = __builtin_amdgcn_mfma_f32_16x16x32_bf16(av, BUF[ks * 4 + n], \
                                                         acc[n], 0, 0, 0);    \
      accd = __builtin_amdgcn_mfma_f32_16x16x32_bf16(av, ones, accd, 0, 0, 0);\
    } }

// one 64-j step: stage loads for J+64 issued first (hide HBM latency under
// compute), h_f frags for J+64 prefetched, compute J from LDS buf SB, then
// write staged tile into buf SB^1, single barrier.
#define STEP(CURBUF, NXTBUF, J, SB) {                                         \
    const int jn = ((J) + 64) & (N - 1);                                      \
    const float4 s0 = *(const float4*)&adjb[(size_t)sr0 * N + jn + sc0];      \
    float4 s1;                                                                \
    if (t < 128) s1 = *(const float4*)&adjb[(size_t)sr1 * N + jn + sc1];      \
    __builtin_amdgcn_sched_barrier(0);                                        \
    LOADJ(NXTBUF, (J) + 64);                                                  \
    __builtin_amdgcn_sched_barrier(0);                                        \
    COMPJ(CURBUF, SB, J);                                                     \
    __builtin_amdgcn_sched_barrier(0);                                        \
    *(float4*)&adjt[(SB) ^ 1][sr0][sc0] = s0;                                 \
    if (t < 128) *(float4*)&adjt[(SB) ^ 1][sr1][sc1] = s1;                    \
    __syncthreads();                                                          \
  }

  bf16x8 bA[8], bB[8];
  LOADJ(bA, 0);
  __syncthreads();                               // uvt + adjt[0] ready
  #pragma unroll 2
  for (int j0 = 0; j0 < N; j0 += 128) {
    STEP(bA, bB, j0, 0);
    STEP(bB, bA, j0 + 64, 1);
  }
#undef LOADJ
#undef COMPJ
#undef STEP

  // epilogue: rows (this wave) i0+rg*16+lg*4+r; denom from accd
  float dn[4];
  #pragma unroll
  for (int r = 0; r < 4; ++r) dn[r] = 1.f / fmaxf(accd[r], 1e-37f);

  #pragma unroll
  for (int n = 0; n < 4; ++n) {
    float csum = 0.f;
    #pragma unroll
    for (int r = 0; r < 4; ++r) csum += fmaxf(acc[n][r] * dn[r], 0.f);
    csum += __shfl_xor(csum, 16);
    csum += __shfl_xor(csum, 32);
    if (lg == 0) atomicAdd(&pooled[b * HC + l * 64 + n * 16 + lr], csum);
  }
}

// ---------------------------------------------------------------------------
// k_head: mean + FC1(relu) + FC2 + softmax.  grid = B.
// ---------------------------------------------------------------------------
__global__ __launch_bounds__(192) void k_head(
    const float* __restrict__ pooled_sums, const float* __restrict__ W1,
    const float* __restrict__ b1, const float* __restrict__ W2,
    const float* __restrict__ b2, float* __restrict__ out)
{
  const int b = blockIdx.x, t = threadIdx.x;
  __shared__ float pooled[HC];
  __shared__ float z[FCH];
  __shared__ float logits[NC];

  if (t < HC) pooled[t] = pooled_sums[b * HC + t] * (1.f / (float)N);
  __syncthreads();

  if (t < FCH) {
    float a = b1[t];
    #pragma unroll 4
    for (int f = 0; f < HC; ++f) a += pooled[f] * W1[(size_t)f * FCH + t];
    z[t] = a > 0.f ? a : 0.f;
  }
  __syncthreads();

  if (t < NC) {
    float a = b2[t];
    #pragma unroll 4
    for (int f = 0; f < FCH; ++f) a += z[f] * W2[(size_t)f * NC + t];
    logits[t] = a;
  }
  __syncthreads();

  if (t == 0) {
    float mxl = logits[0];
    for (int c = 1; c < NC; ++c) mxl = fmaxf(mxl, logits[c]);
    float e[NC], sum = 0.f;
    for (int c = 0; c < NC; ++c) { e[c] = __expf(logits[c] - mxl); sum += e[c]; }
    const float inv = 1.f / sum;
    for (int c = 0; c < NC; ++c) out[b * NC + c] = e[c] * inv;
  }
}

// ---------------------------------------------------------------------------
extern "C" void kernel_launch(void* const* d_in, const int* in_sizes, int n_in,
                              void* d_out, int out_size, void* d_ws, size_t ws_size,
                              hipStream_t stream)
{
  const float* x   = (const float*)d_in[0];
  const float* adj = (const float*)d_in[1];
  const float* Ws  = (const float*)d_in[2];
  const float* a1  = (const float*)d_in[3];
  const float* a2  = (const float*)d_in[4];
  const float* W1  = (const float*)d_in[5];
  const float* b1  = (const float*)d_in[6];
  const float* W2  = (const float*)d_in[7];
  const float* b2  = (const float*)d_in[8];
  float* out = (float*)d_out;

  // workspace layout (16B aligned chunks)
  unsigned short* h_f   = (unsigned short*)d_ws;                       // 6.29 MB
  float*          f1    = (float*)(h_f + (size_t)B * HC * N);          // 196 KB
  float*          f2    = f1 + (size_t)NL * B * N;                     // 196 KB
  float*          pooled= f2 + (size_t)NL * B * N;                     // 12 KB
  unsigned short* wt_hi = (unsigned short*)(pooled + B * HC + 16);     // 48 KB
  unsigned short* wt_lo = wt_hi + (size_t)HC * NF;                     // 48 KB

  k_wt  <<<96,  256, 0, stream>>>(Ws, wt_hi, wt_lo, pooled);
  k_feat<<<256, 256, 0, stream>>>(x, wt_hi, wt_lo, a1, a2, h_f, f1, f2);
  k_att <<<512, 384, 0, stream>>>(adj, h_f, f1, f2, pooled);
  k_head<<<B, 192, 0, stream>>>(pooled, W1, b1, W2, b2, out);
}

// Round 10
// 85.741 us; speedup vs baseline: 1.5096x; 1.0168x over previous
//
#include <hip/hip_runtime.h>

#define B 16
#define N 1024
#define NF 128
#define NL 3
#define AH 64
#define HC 192   // NL*AH
#define FCH 128
#define NC 10
#define L2E 1.44269504088896f
#define PAD 68   // adj tile row stride (floats): conflict-free ds_read_b128

typedef __attribute__((ext_vector_type(8))) short bf16x8;
typedef __attribute__((ext_vector_type(4))) float f32x4;
typedef __attribute__((ext_vector_type(4))) unsigned int u32x4;

static __device__ __forceinline__ unsigned short f2bf(float f) {
  unsigned int x = __builtin_bit_cast(unsigned int, f);
  return (unsigned short)((x + 0x7fffu + ((x >> 16) & 1u)) >> 16);   // RNE
}
static __device__ __forceinline__ float bf2f(unsigned short u) {
  unsigned int x = ((unsigned int)u) << 16;
  return __builtin_bit_cast(float, x);
}

// ---------------------------------------------------------------------------
// k_wt: Ws -> bf16 hi/lo in MFMA-FRAGMENT order:
//   idx = ((n*4+kf)*64+lane)*8+e ; col=n*16+(lane&15) ; k=kf*32+(lane>>4)*8+e
// Also zeroes pooled. grid = 96 x 256.
// ---------------------------------------------------------------------------
__global__ __launch_bounds__(256) void k_wt(
    const float* __restrict__ Ws, unsigned short* __restrict__ wt_hi,
    unsigned short* __restrict__ wt_lo, float* __restrict__ pooled)
{
  const int idx = blockIdx.x * 256 + threadIdx.x;     // 0..24575
  const int n = idx >> 11;
  const int kf = (idx >> 9) & 3;
  const int lane = (idx >> 3) & 63;
  const int e = idx & 7;
  const int col = n * 16 + (lane & 15);
  const int k = kf * 32 + (lane >> 4) * 8 + e;
  const float w = Ws[(size_t)((col >> 6) * NF + k) * AH + (col & 63)];
  const unsigned short hi = f2bf(w);
  wt_hi[idx] = hi;
  wt_lo[idx] = f2bf(w - bf2f(hi));
  if (idx < B * HC) pooled[idx] = 0.f;
}

// ---------------------------------------------------------------------------
// k_feat: 64 nodes/block, split-bf16 MFMA (x = xhi+xlo, W = whi+wlo);
// x staged coalesced via LDS (pad 132); outputs h in FRAGMENT order h_f +
// f1/f2 f32 pre-scaled by log2e. grid = 256 x 256.
// ---------------------------------------------------------------------------
__global__ __launch_bounds__(256) void k_feat(
    const float* __restrict__ x,
    const unsigned short* __restrict__ wt_hi, const unsigned short* __restrict__ wt_lo,
    const float* __restrict__ a1, const float* __restrict__ a2,
    unsigned short* __restrict__ h_f, float* __restrict__ f1g,
    float* __restrict__ f2g)
{
  __shared__ float xs[64][132];                  // 33.8KB; reused as hlds below
  unsigned short (*hlds)[72] = (unsigned short(*)[72])&xs[0][0];  // 27.6KB overlay
  const int t = threadIdx.x;
  const int n0g = blockIdx.x * 64;
  const int gb = n0g >> 10, nl0 = n0g & 1023;
  const int wv = t >> 6, lane = t & 63;
  const int lr = lane & 15, lg = lane >> 4;

  // stage x coalesced: 2048 float4
  #pragma unroll
  for (int p = 0; p < 8; ++p) {
    const int q = p * 256 + t;
    const int row = q >> 5, c4 = (q & 31) * 4;
    *(float4*)&xs[row][c4] = *(const float4*)&x[(size_t)(n0g + row) * NF + c4];
  }
  __syncthreads();

  // per-lane fragment read (2-way LDS = free) + split-bf16 convert
  bf16x8 xhi[4], xlo[4];
  const int lrow = wv * 16 + lr;
  #pragma unroll
  for (int kf = 0; kf < 4; ++kf) {
    const float4 q0 = *(const float4*)&xs[lrow][kf * 32 + lg * 8];
    const float4 q1 = *(const float4*)&xs[lrow][kf * 32 + lg * 8 + 4];
    const float xv[8] = {q0.x, q0.y, q0.z, q0.w, q1.x, q1.y, q1.z, q1.w};
    #pragma unroll
    for (int e = 0; e < 8; ++e) {
      const unsigned short hi = f2bf(xv[e]);
      xhi[kf][e] = (short)hi;
      xlo[kf][e] = (short)f2bf(xv[e] - bf2f(hi));
    }
  }
  __syncthreads();                               // xs dead; hlds may reuse it

  f32x4 acc[12];
  #pragma unroll
  for (int n = 0; n < 12; ++n) acc[n] = (f32x4){0.f, 0.f, 0.f, 0.f};

  #pragma unroll
  for (int n = 0; n < 12; ++n) {
    #pragma unroll
    for (int kf = 0; kf < 4; ++kf) {
      const int fo = ((n * 4 + kf) << 9) + lane * 8;
      const bf16x8 whi = *(const bf16x8*)&wt_hi[fo];
      const bf16x8 wlo = *(const bf16x8*)&wt_lo[fo];
      acc[n] = __builtin_amdgcn_mfma_f32_16x16x32_bf16(xhi[kf], whi, acc[n], 0, 0, 0);
      acc[n] = __builtin_amdgcn_mfma_f32_16x16x32_bf16(xhi[kf], wlo, acc[n], 0, 0, 0);
      acc[n] = __builtin_amdgcn_mfma_f32_16x16x32_bf16(xlo[kf], whi, acc[n], 0, 0, 0);
    }
  }

  // f1/f2 (exact f32), pre-scaled by log2e
  float s1[3][4], s2[3][4];
  #pragma unroll
  for (int l = 0; l < 3; ++l)
    #pragma unroll
    for (int r = 0; r < 4; ++r) { s1[l][r] = 0.f; s2[l][r] = 0.f; }
  #pragma unroll
  for (int n = 0; n < 12; ++n) {
    const int col = n * 16 + lr;
    const float a1v = a1[col] * L2E, a2v = a2[col] * L2E;
    const int l = n >> 2;
    #pragma unroll
    for (int r = 0; r < 4; ++r) {
      s1[l][r] += acc[n][r] * a1v;
      s2[l][r] += acc[n][r] * a2v;
    }
  }
  #pragma unroll
  for (int off = 1; off < 16; off <<= 1)
    #pragma unroll
    for (int l = 0; l < 3; ++l)
      #pragma unroll
      for (int r = 0; r < 4; ++r) {
        s1[l][r] += __shfl_xor(s1[l][r], off);
        s2[l][r] += __shfl_xor(s2[l][r], off);
      }
  if (lr == 0) {
    #pragma unroll
    for (int l = 0; l < 3; ++l)
      #pragma unroll
      for (int r = 0; r < 4; ++r) {
        const int rw = n0g + wv * 16 + lg * 4 + r;
        f1g[(size_t)l * (B * N) + rw] = s1[l][r];
        f2g[(size_t)l * (B * N) + rw] = s2[l][r];
      }
  }

  // pack bf16 -> LDS transpose (node-local index = wv*16+lg*4+r)
  #pragma unroll
  for (int n = 0; n < 12; ++n) {
    const int col = n * 16 + lr;
    #pragma unroll
    for (int rp = 0; rp < 2; ++rp) {
      const unsigned int pr = (unsigned int)f2bf(acc[n][rp * 2]) |
                              ((unsigned int)f2bf(acc[n][rp * 2 + 1]) << 16);
      *(unsigned int*)&hlds[col][wv * 16 + lg * 4 + rp * 2] = pr;
    }
  }
  __syncthreads();
  // fragment-order store: element (b,l,n,jslot,lane,e) = h[col=l*64+n*16+(lane&15)]
  //                                                       [j = jslot*32+(lane>>4)*8+e]
  #pragma unroll
  for (int p = 0; p < 6; ++p) {
    const int widx = p * 256 + t;                  // 0..1535
    const int lane_w = widx & 63;
    const int jb2 = (widx >> 6) & 1;
    const int n_w = (widx >> 7) & 3;
    const int l_w = widx >> 9;
    const int col = l_w * 64 + n_w * 16 + (lane_w & 15);
    const int jloc = jb2 * 32 + (lane_w >> 4) * 8;
    const size_t off =
        ((((size_t)(gb * 3 + l_w) * 4 + n_w) * 32 + (nl0 >> 5) + jb2) * 64 + lane_w) * 8;
    *(uint4*)&h_f[off] = *(const uint4*)&hlds[col][jloc];
  }
}

// ---------------------------------------------------------------------------
// k_att: fused 3-layer GAT attention + MFMA PV + ones-column denominator +
// relu + pool. adj streamed via 2-DEEP register stage -> double-buffered LDS
// tile; h_f double-buffered in regs; P = max(A*u, C*v) (no cmp/select).
// grid = 512 x 384 (6 waves = layer x rowgroup); __launch_bounds__(384,3)
// caps VGPR at ~170 so the buffers actually live in registers.
// ---------------------------------------------------------------------------
__global__ __launch_bounds__(384, 3) void k_att(
    const float* __restrict__ adj, const unsigned short* __restrict__ h_f,
    const float* __restrict__ f1, const float* __restrict__ f2,
    float* __restrict__ pooled)
{
  const int bid = blockIdx.x;
  const int blk = (bid & 7) * 64 + (bid >> 3);   // 8 XCDs x 64: 2 batches/XCD
  const int b = blk >> 5;
  const int i0 = (blk & 31) * 32;
  const int t = threadIdx.x;
  const int w = t >> 6, lane = t & 63;
  const int l = w >> 1, rg = w & 1;
  const int lr = lane & 15, lg = lane >> 4;

  __shared__ float uvt[NL][2][N];          // 24 KB u/v tables
  __shared__ float adjt[2][32][PAD];       // 17.4 KB double-buffered adj tile

  // ---- prologue: u/v tables + full-N unmasked max ----
  const float* f2p = f2 + (size_t)l * (B * N) + b * N;
  float mx = -1e30f;
  #pragma unroll
  for (int ch = 0; ch < 4; ++ch) {
    const int jb = ch * 256 + lane * 4;
    const float4 q = *(const float4*)&f2p[jb];
    mx = fmaxf(mx, fmaxf(fmaxf(q.x, q.y), fmaxf(q.z, q.w)));
    if ((ch >> 1) == rg) {
      *(float4*)&uvt[l][0][jb] =
          (float4){exp2f(q.x), exp2f(q.y), exp2f(q.z), exp2f(q.w)};
      *(float4*)&uvt[l][1][jb] =
          (float4){exp2f(0.2f * q.x), exp2f(0.2f * q.y), exp2f(0.2f * q.z), exp2f(0.2f * q.w)};
    }
  }
  #pragma unroll
  for (int off = 1; off < 64; off <<= 1) mx = fmaxf(mx, __shfl_xor(mx, off));

  const float f1r = f1[(size_t)l * (B * N) + b * N + i0 + rg * 16 + lr];
  const float tts = f1r + mx;
  const float sr = fmaxf(tts, 0.f) + 0.2f * fminf(tts, 0.f);  // valid upper bound
  const float A = exp2f(f1r - sr);
  const float C = exp2f(0.2f * f1r - sr);

  const float* adjb = adj + ((size_t)(b * N + i0)) * N;   // 32 rows x N
  const unsigned short* hfb = h_f + ((size_t)(b * 3 + l)) * 65536;
  const float* ut = &uvt[l][0][0];
  const float* vt = &uvt[l][1][0];
  const bf16x8 ones = {(short)0x3F80, (short)0x3F80, (short)0x3F80, (short)0x3F80,
                       (short)0x3F80, (short)0x3F80, (short)0x3F80, (short)0x3F80};

  // staging coords: flat q in [0,512): row=q>>4, c4=q&15; thread t does q=t
  // and (t<128) q=t+384
  const int sr0 = t >> 4, sc0 = (t & 15) * 4;
  const int sr1 = (t + 384) >> 4, sc1 = ((t + 384) & 15) * 4;

  f32x4 acc[4];
  #pragma unroll
  for (int n = 0; n < 4; ++n) acc[n] = (f32x4){0.f, 0.f, 0.f, 0.f};
  f32x4 accd = (f32x4){0.f, 0.f, 0.f, 0.f};

#define STAGE_ISSUE(S0, S1, J) {                                              \
    const int jn = (J) & (N - 1);                                             \
    S0 = *(const float4*)&adjb[(size_t)sr0 * N + jn + sc0];                   \
    if (t < 128) S1 = *(const float4*)&adjb[(size_t)sr1 * N + jn + sc1];      \
  }
#define STAGE_WRITE(S0, S1, SB) {                                             \
    *(float4*)&adjt[SB][sr0][sc0] = S0;                                       \
    if (t < 128) *(float4*)&adjt[SB][sr1][sc1] = S1;                          \
  }

#define LOADJ(BUF, J) {                                                       \
    const int jj = (J) & (N - 1);                                             \
    _Pragma("unroll")                                                         \
    for (int q = 0; q < 8; ++q) {                                             \
      const int ks = q >> 2, n = q & 3;                                       \
      BUF[q] = *(const bf16x8*)&hfb[(((size_t)n * 32 + (jj >> 5) + ks) * 64 + \
                                     lane) * 8];                              \
    } }

#define COMPJ(BUF, SB, J) {                                                   \
    _Pragma("unroll")                                                         \
    for (int ks = 0; ks < 2; ++ks) {                                          \
      const int kb = (J) + ks * 32 + lg * 8;                                  \
      const float4 u0 = *(const float4*)&ut[kb];                              \
      const float4 u1 = *(const float4*)&ut[kb + 4];                          \
      const float4 v0 = *(const float4*)&vt[kb];                              \
      const float4 v1 = *(const float4*)&vt[kb + 4];                          \
      const float4 m0 = *(const float4*)&adjt[SB][rg * 16 + lr][ks * 32 + lg * 8];     \
      const float4 m1 = *(const float4*)&adjt[SB][rg * 16 + lr][ks * 32 + lg * 8 + 4]; \
      const float uu[8] = {u0.x, u0.y, u0.z, u0.w, u1.x, u1.y, u1.z, u1.w};   \
      const float vv[8] = {v0.x, v0.y, v0.z, v0.w, v1.x, v1.y, v1.z, v1.w};   \
      const float mm[8] = {m0.x, m0.y, m0.z, m0.w, m1.x, m1.y, m1.z, m1.w};   \
      unsigned int pk[4];                                                     \
      _Pragma("unroll")                                                       \
      for (int ep = 0; ep < 4; ++ep) {                                        \
        unsigned int pr[2];                                                   \
        _Pragma("unroll")                                                     \
        for (int h = 0; h < 2; ++h) {                                         \
          const int e = ep * 2 + h;                                           \
          /* leaky(t)=max(t,0.2t); exp2 monotone => P=max(A*u, C*v), *adj */  \
          const float p = fmaxf(A * uu[e], C * vv[e]) * mm[e];                \
          pr[h] = __builtin_bit_cast(unsigned int, p) + 0x8000u;              \
        }                                                                     \
        pk[ep] = __builtin_amdgcn_perm(pr[1], pr[0], 0x07060302u);            \
      }                                                                       \
      const u32x4 pkv = {pk[0], pk[1], pk[2], pk[3]};                         \
      const bf16x8 av = __builtin_bit_cast(bf16x8, pkv);                      \
      _Pragma("unroll")                                                       \
      for (int n = 0; n < 4; ++n)                                             \
        acc[n] = __builtin_amdgcn_mfma_f32_16x16x32_bf16(av, BUF[ks * 4 + n], \
                                                         acc[n], 0, 0, 0);    \
      accd = __builtin_amdgcn_mfma_f32_16x16x32_bf16(av, ones, accd, 0, 0, 0);\
    } }

  bf16x8 bA[8], bB[8];
  float4 SA0, SA1, SB0, SB1;

  // prologue pipeline fill: SA <- j0 (write now), SB <- j64 (in flight)
  STAGE_ISSUE(SA0, SA1, 0);
  STAGE_ISSUE(SB0, SB1, 64);
  LOADJ(bA, 0);
  STAGE_WRITE(SA0, SA1, 0);                      // waits only SA (oldest)
  __syncthreads();                               // uvt + adjt[0] ready

  for (int j0 = 0; j0 < N; j0 += 128) {
    // --- half A: compute tile j0 from adjt[0]/bA; SB(j0+64) in flight ---
    STAGE_ISSUE(SA0, SA1, j0 + 128);
    LOADJ(bB, j0 + 64);
    __builtin_amdgcn_sched_barrier(0);
    COMPJ(bA, 0, j0);
    __builtin_amdgcn_sched_barrier(0);
    STAGE_WRITE(SB0, SB1, 1);                    // waits only SB (a step old)
    __syncthreads();
    // --- half B: compute tile j0+64 from adjt[1]/bB; SA(j0+128) in flight ---
    STAGE_ISSUE(SB0, SB1, j0 + 192);
    LOADJ(bA, j0 + 128);
    __builtin_amdgcn_sched_barrier(0);
    COMPJ(bB, 1, j0 + 64);
    __builtin_amdgcn_sched_barrier(0);
    STAGE_WRITE(SA0, SA1, 0);                    // waits only SA
    __syncthreads();
  }
#undef STAGE_ISSUE
#undef STAGE_WRITE
#undef LOADJ
#undef COMPJ

  // epilogue: rows (this wave) i0+rg*16+lg*4+r; denom from accd
  float dn[4];
  #pragma unroll
  for (int r = 0; r < 4; ++r) dn[r] = 1.f / fmaxf(accd[r], 1e-37f);

  #pragma unroll
  for (int n = 0; n < 4; ++n) {
    float csum = 0.f;
    #pragma unroll
    for (int r = 0; r < 4; ++r) csum += fmaxf(acc[n][r] * dn[r], 0.f);
    csum += __shfl_xor(csum, 16);
    csum += __shfl_xor(csum, 32);
    if (lg == 0) atomicAdd(&pooled[b * HC + l * 64 + n * 16 + lr], csum);
  }
}

// ---------------------------------------------------------------------------
// k_head: mean + FC1(relu) + FC2 + softmax.  grid = B.
// ---------------------------------------------------------------------------
__global__ __launch_bounds__(192) void k_head(
    const float* __restrict__ pooled_sums, const float* __restrict__ W1,
    const float* __restrict__ b1, const float* __restrict__ W2,
    const float* __restrict__ b2, float* __restrict__ out)
{
  const int b = blockIdx.x, t = threadIdx.x;
  __shared__ float pooled[HC];
  __shared__ float z[FCH];
  __shared__ float logits[NC];

  if (t < HC) pooled[t] = pooled_sums[b * HC + t] * (1.f / (float)N);
  __syncthreads();

  if (t < FCH) {
    float a = b1[t];
    #pragma unroll 4
    for (int f = 0; f < HC; ++f) a += pooled[f] * W1[(size_t)f * FCH + t];
    z[t] = a > 0.f ? a : 0.f;
  }
  __syncthreads();

  if (t < NC) {
    float a = b2[t];
    #pragma unroll 4
    for (int f = 0; f < FCH; ++f) a += z[f] * W2[(size_t)f * NC + t];
    logits[t] = a;
  }
  __syncthreads();

  if (t == 0) {
    float mxl = logits[0];
    for (int c = 1; c < NC; ++c) mxl = fmaxf(mxl, logits[c]);
    float e[NC], sum = 0.f;
    for (int c = 0; c < NC; ++c) { e[c] = __expf(logits[c] - mxl); sum += e[c]; }
    const float inv = 1.f / sum;
    for (int c = 0; c < NC; ++c) out[b * NC + c] = e[c] * inv;
  }
}

// ---------------------------------------------------------------------------
extern "C" void kernel_launch(void* const* d_in, const int* in_sizes, int n_in,
                              void* d_out, int out_size, void* d_ws, size_t ws_size,
                              hipStream_t stream)
{
  const float* x   = (const float*)d_in[0];
  const float* adj = (const float*)d_in[1];
  const float* Ws  = (const float*)d_in[2];
  const float* a1  = (const float*)d_in[3];
  const float* a2  = (const float*)d_in[4];
  const float* W1  = (const float*)d_in[5];
  const float* b1  = (const float*)d_in[6];
  const float* W2  = (const float*)d_in[7];
  const float* b2  = (const float*)d_in[8];
  float* out = (float*)d_out;

  // workspace layout (16B aligned chunks)
  unsigned short* h_f   = (unsigned short*)d_ws;                       // 6.29 MB
  float*          f1    = (float*)(h_f + (size_t)B * HC * N);          // 196 KB
  float*          f2    = f1 + (size_t)NL * B * N;                     // 196 KB
  float*          pooled= f2 + (size_t)NL * B * N;                     // 12 KB
  unsigned short* wt_hi = (unsigned short*)(pooled + B * HC + 16);     // 48 KB
  unsigned short* wt_lo = wt_hi + (size_t)HC * NF;                     // 48 KB

  k_wt  <<<96,  256, 0, stream>>>(Ws, wt_hi, wt_lo, pooled);
  k_feat<<<256, 256, 0, stream>>>(x, wt_hi, wt_lo, a1, a2, h_f, f1, f2);
  k_att <<<512, 384, 0, stream>>>(adj, h_f, f1, f2, pooled);
  k_head<<<B, 192, 0, stream>>>(pooled, W1, b1, W2, b2, out);
}

// Round 11
// 71.612 us; speedup vs baseline: 1.8074x; 1.1973x over previous
//
#include <hip/hip_runtime.h>

#define B 16
#define N 1024
#define NF 128
#define NL 3
#define AH 64
#define HC 192   // NL*AH
#define FCH 128
#define NC 10
#define L2E 1.44269504088896f

typedef __attribute__((ext_vector_type(8))) short bf16x8;
typedef __attribute__((ext_vector_type(4))) float f32x4;
typedef __attribute__((ext_vector_type(4))) unsigned int u32x4;

static __device__ __forceinline__ unsigned short f2bf(float f) {
  unsigned int x = __builtin_bit_cast(unsigned int, f);
  return (unsigned short)((x + 0x7fffu + ((x >> 16) & 1u)) >> 16);   // RNE
}
static __device__ __forceinline__ float bf2f(unsigned short u) {
  unsigned int x = ((unsigned int)u) << 16;
  return __builtin_bit_cast(float, x);
}

// ---------------------------------------------------------------------------
// k_feat: 64 nodes/block; Ws staged per-layer into LDS (hi/lo bf16, coalesced)
// -> all MFMA operands LDS-local. Outputs h in FRAGMENT order h_f + f1/f2 f32
// pre-scaled by log2e. grid = 256 x 256. LDS 68.6KB -> 2 blocks/CU.
// ---------------------------------------------------------------------------
__global__ __launch_bounds__(256) void k_feat(
    const float* __restrict__ x, const float* __restrict__ Ws,
    const float* __restrict__ a1, const float* __restrict__ a2,
    unsigned short* __restrict__ h_f, float* __restrict__ f1g,
    float* __restrict__ f2g)
{
  __shared__ float xs[64][132];                  // 33.8KB; hlds overlays later
  __shared__ unsigned short wl[2][64][136];      // 34.8KB hi/lo for one layer
  unsigned short (*hlds)[72] = (unsigned short(*)[72])&xs[0][0];  // 27.6KB
  const int t = threadIdx.x;
  const int n0g = blockIdx.x * 64;
  const int gb = n0g >> 10, nl0 = n0g & 1023;
  const int wv = t >> 6, lane = t & 63;
  const int lr = lane & 15, lg = lane >> 4;
  const int lrow = wv * 16 + lr;

  // stage x coalesced: 2048 float4
  #pragma unroll
  for (int p = 0; p < 8; ++p) {
    const int q = p * 256 + t;
    const int row = q >> 5, c4 = (q & 31) * 4;
    *(float4*)&xs[row][c4] = *(const float4*)&x[(size_t)(n0g + row) * NF + c4];
  }
  __syncthreads();

  // per-lane x fragments + split-bf16 convert
  bf16x8 xhi[4], xlo[4];
  #pragma unroll
  for (int kf = 0; kf < 4; ++kf) {
    const float4 q0 = *(const float4*)&xs[lrow][kf * 32 + lg * 8];
    const float4 q1 = *(const float4*)&xs[lrow][kf * 32 + lg * 8 + 4];
    const float xv[8] = {q0.x, q0.y, q0.z, q0.w, q1.x, q1.y, q1.z, q1.w};
    #pragma unroll
    for (int e = 0; e < 8; ++e) {
      const unsigned short hi = f2bf(xv[e]);
      xhi[kf][e] = (short)hi;
      xlo[kf][e] = (short)f2bf(xv[e] - bf2f(hi));
    }
  }

  f32x4 acc[12];
  #pragma unroll
  for (int n = 0; n < 12; ++n) acc[n] = (f32x4){0.f, 0.f, 0.f, 0.f};

  for (int l = 0; l < 3; ++l) {
    __syncthreads();                             // prior wl reads done
    // stage Ws[l] -> wl hi/lo: 1024 (col,oct) tasks, coalesced global reads
    #pragma unroll
    for (int p = 0; p < 4; ++p) {
      const int task = p * 256 + t;
      const int col = task & 63, oct = task >> 6;
      bf16x8 hv, lv;
      #pragma unroll
      for (int i = 0; i < 8; ++i) {
        const float w = Ws[((size_t)l * NF + oct * 8 + i) * AH + col];
        const unsigned short hi = f2bf(w);
        hv[i] = (short)hi;
        lv[i] = (short)f2bf(w - bf2f(hi));
      }
      *(bf16x8*)&wl[0][col][oct * 8] = hv;
      *(bf16x8*)&wl[1][col][oct * 8] = lv;
    }
    __syncthreads();

    #pragma unroll
    for (int n2 = 0; n2 < 4; ++n2) {
      const int n = l * 4 + n2;
      #pragma unroll
      for (int kf = 0; kf < 4; ++kf) {
        const bf16x8 whi = *(const bf16x8*)&wl[0][n2 * 16 + lr][kf * 32 + lg * 8];
        const bf16x8 wlo = *(const bf16x8*)&wl[1][n2 * 16 + lr][kf * 32 + lg * 8];
        acc[n] = __builtin_amdgcn_mfma_f32_16x16x32_bf16(xhi[kf], whi, acc[n], 0, 0, 0);
        acc[n] = __builtin_amdgcn_mfma_f32_16x16x32_bf16(xhi[kf], wlo, acc[n], 0, 0, 0);
        acc[n] = __builtin_amdgcn_mfma_f32_16x16x32_bf16(xlo[kf], whi, acc[n], 0, 0, 0);
      }
    }
  }

  // f1/f2 (exact f32), pre-scaled by log2e
  float s1[3][4], s2[3][4];
  #pragma unroll
  for (int l = 0; l < 3; ++l)
    #pragma unroll
    for (int r = 0; r < 4; ++r) { s1[l][r] = 0.f; s2[l][r] = 0.f; }
  #pragma unroll
  for (int n = 0; n < 12; ++n) {
    const int col = n * 16 + lr;
    const float a1v = a1[col] * L2E, a2v = a2[col] * L2E;
    const int l = n >> 2;
    #pragma unroll
    for (int r = 0; r < 4; ++r) {
      s1[l][r] += acc[n][r] * a1v;
      s2[l][r] += acc[n][r] * a2v;
    }
  }
  #pragma unroll
  for (int off = 1; off < 16; off <<= 1)
    #pragma unroll
    for (int l = 0; l < 3; ++l)
      #pragma unroll
      for (int r = 0; r < 4; ++r) {
        s1[l][r] += __shfl_xor(s1[l][r], off);
        s2[l][r] += __shfl_xor(s2[l][r], off);
      }
  if (lr == 0) {
    #pragma unroll
    for (int l = 0; l < 3; ++l)
      #pragma unroll
      for (int r = 0; r < 4; ++r) {
        const int rw = n0g + wv * 16 + lg * 4 + r;
        f1g[(size_t)l * (B * N) + rw] = s1[l][r];
        f2g[(size_t)l * (B * N) + rw] = s2[l][r];
      }
  }

  __syncthreads();                               // xs dead; hlds reuses it
  // pack bf16 -> LDS transpose (node-local index = wv*16+lg*4+r)
  #pragma unroll
  for (int n = 0; n < 12; ++n) {
    const int col = n * 16 + lr;
    #pragma unroll
    for (int rp = 0; rp < 2; ++rp) {
      const unsigned int pr = (unsigned int)f2bf(acc[n][rp * 2]) |
                              ((unsigned int)f2bf(acc[n][rp * 2 + 1]) << 16);
      *(unsigned int*)&hlds[col][wv * 16 + lg * 4 + rp * 2] = pr;
    }
  }
  __syncthreads();
  // fragment-order store: element (b,l,n,jslot,lane,e) = h[col=l*64+n*16+(lane&15)]
  //                                                       [j = jslot*32+(lane>>4)*8+e]
  #pragma unroll
  for (int p = 0; p < 6; ++p) {
    const int widx = p * 256 + t;                  // 0..1535
    const int lane_w = widx & 63;
    const int jb2 = (widx >> 6) & 1;
    const int n_w = (widx >> 7) & 3;
    const int l_w = widx >> 9;
    const int col = l_w * 64 + n_w * 16 + (lane_w & 15);
    const int jloc = jb2 * 32 + (lane_w >> 4) * 8;
    const size_t off =
        ((((size_t)(gb * 3 + l_w) * 4 + n_w) * 32 + (nl0 >> 5) + jb2) * 64 + lane_w) * 8;
    *(uint4*)&h_f[off] = *(const uint4*)&hlds[col][jloc];
  }
}

// ---------------------------------------------------------------------------
// k_att: fused 3-layer GAT attention + MFMA PV + ones-column denominator +
// relu + pool. adj staged as U8 tile (4x fewer LDS bytes, conflict-free b64
// reads at pad 88); 2-deep reg stage; h_f reg double-buffer. grid = 1024 x
// 192 (3 waves, wave = layer, 16 rows/block; 4 independent blocks/CU).
// ---------------------------------------------------------------------------
__global__ __launch_bounds__(192, 3) void k_att(
    const float* __restrict__ adj, const unsigned short* __restrict__ h_f,
    const float* __restrict__ f1, const float* __restrict__ f2,
    float* __restrict__ pooled)
{
  const int bid = blockIdx.x;
  const int blk = (bid & 7) * 128 + (bid >> 3);  // 8 XCDs x 128: 2 batches/XCD
  const int b = blk >> 6;
  const int i0 = (blk & 63) * 16;
  const int t = threadIdx.x;
  const int l = t >> 6, lane = t & 63;
  const int lr = lane & 15, lg = lane >> 4;

  __shared__ float uvt[NL][2][N];                // 24 KB u/v tables
  __shared__ unsigned char adjm[2][16][88];      // 2.75 KB u8 adj tiles

  // ---- prologue: u/v tables + full-N unmasked max (wave l = layer l) ----
  const float* f2p = f2 + (size_t)l * (B * N) + b * N;
  float mx = -1e30f;
  #pragma unroll
  for (int ch = 0; ch < 4; ++ch) {
    const int jb = ch * 256 + lane * 4;
    const float4 q = *(const float4*)&f2p[jb];
    mx = fmaxf(mx, fmaxf(fmaxf(q.x, q.y), fmaxf(q.z, q.w)));
    *(float4*)&uvt[l][0][jb] =
        (float4){exp2f(q.x), exp2f(q.y), exp2f(q.z), exp2f(q.w)};
    *(float4*)&uvt[l][1][jb] =
        (float4){exp2f(0.2f * q.x), exp2f(0.2f * q.y), exp2f(0.2f * q.z), exp2f(0.2f * q.w)};
  }
  #pragma unroll
  for (int off = 1; off < 64; off <<= 1) mx = fmaxf(mx, __shfl_xor(mx, off));

  const float f1r = f1[(size_t)l * (B * N) + b * N + i0 + lr];
  const float tts = f1r + mx;
  const float sr = fmaxf(tts, 0.f) + 0.2f * fminf(tts, 0.f);  // valid upper bound
  const float A = exp2f(f1r - sr);
  const float C = exp2f(0.2f * f1r - sr);

  const float* adjb = adj + ((size_t)(b * N + i0)) * N;   // 16 rows x N
  const unsigned short* hfb = h_f + ((size_t)(b * 3 + l)) * 65536;
  const float* ut = &uvt[l][0][0];
  const float* vt = &uvt[l][1][0];
  const bf16x8 ones = {(short)0x3F80, (short)0x3F80, (short)0x3F80, (short)0x3F80,
                       (short)0x3F80, (short)0x3F80, (short)0x3F80, (short)0x3F80};

  // staging coords: 256 float4 tasks per 16x64 tile; thread t does q=t and
  // (t<64) q=t+192
  const int s_r0 = t >> 4, s_c0 = (t & 15) * 4;
  const int s_r1 = (t + 192) >> 4, s_c1 = ((t + 192) & 15) * 4;

  f32x4 acc[4];
  #pragma unroll
  for (int n = 0; n < 4; ++n) acc[n] = (f32x4){0.f, 0.f, 0.f, 0.f};
  f32x4 accd = (f32x4){0.f, 0.f, 0.f, 0.f};

#define PACK4(U) (((U).x ? 1u : 0u) | ((U).y ? 0x100u : 0u) | \
                  ((U).z ? 0x10000u : 0u) | ((U).w ? 0x1000000u : 0u))

#define STAGE_ISSUE(S0, S1, J) {                                              \
    const int jn = (J) & (N - 1);                                             \
    S0 = *(const uint4*)&adjb[(size_t)s_r0 * N + jn + s_c0];                  \
    if (t < 64) S1 = *(const uint4*)&adjb[(size_t)s_r1 * N + jn + s_c1];      \
  }
#define STAGE_WRITE(S0, S1, SB) {                                             \
    *(unsigned int*)&adjm[SB][s_r0][s_c0] = PACK4(S0);                        \
    if (t < 64) *(unsigned int*)&adjm[SB][s_r1][s_c1] = PACK4(S1);            \
  }

#define LOADJ(BUF, J) {                                                       \
    const int jj = (J) & (N - 1);                                             \
    _Pragma("unroll")                                                         \
    for (int q = 0; q < 8; ++q) {                                             \
      const int ks = q >> 2, n = q & 3;                                       \
      BUF[q] = *(const bf16x8*)&hfb[(((size_t)n * 32 + (jj >> 5) + ks) * 64 + \
                                     lane) * 8];                              \
    } }

#define COMPJ(BUF, SB, J) {                                                   \
    _Pragma("unroll")                                                         \
    for (int ks = 0; ks < 2; ++ks) {                                          \
      const int kb = (J) + ks * 32 + lg * 8;                                  \
      const float4 u0 = *(const float4*)&ut[kb];                              \
      const float4 u1 = *(const float4*)&ut[kb + 4];                          \
      const float4 v0 = *(const float4*)&vt[kb];                              \
      const float4 v1 = *(const float4*)&vt[kb + 4];                          \
      const uint2 mw = *(const uint2*)&adjm[SB][lr][ks * 32 + lg * 8];        \
      const float uu[8] = {u0.x, u0.y, u0.z, u0.w, u1.x, u1.y, u1.z, u1.w};   \
      const float vv[8] = {v0.x, v0.y, v0.z, v0.w, v1.x, v1.y, v1.z, v1.w};   \
      unsigned int pk[4];                                                     \
      _Pragma("unroll")                                                       \
      for (int ep = 0; ep < 4; ++ep) {                                        \
        unsigned int pr[2];                                                   \
        _Pragma("unroll")                                                     \
        for (int h = 0; h < 2; ++h) {                                         \
          const int e = ep * 2 + h;                                           \
          const unsigned int mby =                                            \
              ((e < 4 ? mw.x : mw.y) >> ((e & 3) * 8)) & 0xffu;               \
          /* leaky(t)=max(t,0.2t); exp2 monotone => P=max(A*u, C*v)*m */      \
          const float p = fmaxf(A * uu[e], C * vv[e]) * (float)mby;           \
          pr[h] = __builtin_bit_cast(unsigned int, p) + 0x8000u;              \
        }                                                                     \
        pk[ep] = __builtin_amdgcn_perm(pr[1], pr[0], 0x07060302u);            \
      }                                                                       \
      const u32x4 pkv = {pk[0], pk[1], pk[2], pk[3]};                         \
      const bf16x8 av = __builtin_bit_cast(bf16x8, pkv);                      \
      _Pragma("unroll")                                                       \
      for (int n = 0; n < 4; ++n)                                             \
        acc[n] = __builtin_amdgcn_mfma_f32_16x16x32_bf16(av, BUF[ks * 4 + n], \
                                                         acc[n], 0, 0, 0);    \
      accd = __builtin_amdgcn_mfma_f32_16x16x32_bf16(av, ones, accd, 0, 0, 0);\
    } }

  bf16x8 bA[8], bB[8];
  uint4 SA0, SA1, SB0, SB1;

  // pipeline fill: SA <- j0 (write now), SB <- j64 (in flight)
  STAGE_ISSUE(SA0, SA1, 0);
  STAGE_ISSUE(SB0, SB1, 64);
  LOADJ(bA, 0);
  STAGE_WRITE(SA0, SA1, 0);                      // waits only SA (oldest)
  __syncthreads();                               // uvt + adjm[0] ready

  for (int j0 = 0; j0 < N; j0 += 128) {
    STAGE_ISSUE(SA0, SA1, j0 + 128);
    LOADJ(bB, j0 + 64);
    __builtin_amdgcn_sched_barrier(0);
    COMPJ(bA, 0, j0);
    __builtin_amdgcn_sched_barrier(0);
    STAGE_WRITE(SB0, SB1, 1);                    // SB is a full step old
    __syncthreads();
    STAGE_ISSUE(SB0, SB1, j0 + 192);
    LOADJ(bA, j0 + 128);
    __builtin_amdgcn_sched_barrier(0);
    COMPJ(bB, 1, j0 + 64);
    __builtin_amdgcn_sched_barrier(0);
    STAGE_WRITE(SA0, SA1, 0);
    __syncthreads();
  }
#undef PACK4
#undef STAGE_ISSUE
#undef STAGE_WRITE
#undef LOADJ
#undef COMPJ

  // epilogue: rows i0+lg*4+r owned by this lane's acc regs; denom from accd
  float dn[4];
  #pragma unroll
  for (int r = 0; r < 4; ++r) dn[r] = 1.f / fmaxf(accd[r], 1e-37f);

  #pragma unroll
  for (int n = 0; n < 4; ++n) {
    float csum = 0.f;
    #pragma unroll
    for (int r = 0; r < 4; ++r) csum += fmaxf(acc[n][r] * dn[r], 0.f);
    csum += __shfl_xor(csum, 16);
    csum += __shfl_xor(csum, 32);
    if (lg == 0) atomicAdd(&pooled[b * HC + l * 64 + n * 16 + lr], csum);
  }
}

// ---------------------------------------------------------------------------
// k_head: mean + FC1(relu) + FC2 + softmax.  grid = B.
// ---------------------------------------------------------------------------
__global__ __launch_bounds__(192) void k_head(
    const float* __restrict__ pooled_sums, const float* __restrict__ W1,
    const float* __restrict__ b1, const float* __restrict__ W2,
    const float* __restrict__ b2, float* __restrict__ out)
{
  const int b = blockIdx.x, t = threadIdx.x;
  __shared__ float pooled[HC];
  __shared__ float z[FCH];
  __shared__ float logits[NC];

  if (t < HC) pooled[t] = pooled_sums[b * HC + t] * (1.f / (float)N);
  __syncthreads();

  if (t < FCH) {
    float a = b1[t];
    #pragma unroll 4
    for (int f = 0; f < HC; ++f) a += pooled[f] * W1[(size_t)f * FCH + t];
    z[t] = a > 0.f ? a : 0.f;
  }
  __syncthreads();

  if (t < NC) {
    float a = b2[t];
    #pragma unroll 4
    for (int f = 0; f < FCH; ++f) a += z[f] * W2[(size_t)f * NC + t];
    logits[t] = a;
  }
  __syncthreads();

  if (t == 0) {
    float mxl = logits[0];
    for (int c = 1; c < NC; ++c) mxl = fmaxf(mxl, logits[c]);
    float e[NC], sum = 0.f;
    for (int c = 0; c < NC; ++c) { e[c] = __expf(logits[c] - mxl); sum += e[c]; }
    const float inv = 1.f / sum;
    for (int c = 0; c < NC; ++c) out[b * NC + c] = e[c] * inv;
  }
}

// ---------------------------------------------------------------------------
extern "C" void kernel_launch(void* const* d_in, const int* in_sizes, int n_in,
                              void* d_out, int out_size, void* d_ws, size_t ws_size,
                              hipStream_t stream)
{
  const float* x   = (const float*)d_in[0];
  const float* adj = (const float*)d_in[1];
  const float* Ws  = (const float*)d_in[2];
  const float* a1  = (const float*)d_in[3];
  const float* a2  = (const float*)d_in[4];
  const float* W1  = (const float*)d_in[5];
  const float* b1  = (const float*)d_in[6];
  const float* W2  = (const float*)d_in[7];
  const float* b2  = (const float*)d_in[8];
  float* out = (float*)d_out;

  // workspace layout (16B aligned chunks)
  unsigned short* h_f   = (unsigned short*)d_ws;                       // 6.29 MB
  float*          f1    = (float*)(h_f + (size_t)B * HC * N);          // 196 KB
  float*          f2    = f1 + (size_t)NL * B * N;                     // 196 KB
  float*          pooled= f2 + (size_t)NL * B * N;                     // 12 KB

  hipMemsetAsync(pooled, 0, (size_t)B * HC * sizeof(float), stream);
  k_feat<<<256, 256, 0, stream>>>(x, Ws, a1, a2, h_f, f1, f2);
  k_att <<<1024, 192, 0, stream>>>(adj, h_f, f1, f2, pooled);
  k_head<<<B, 192, 0, stream>>>(pooled, W1, b1, W2, b2, out);
}

// Round 12
// 71.055 us; speedup vs baseline: 1.8216x; 1.0078x over previous
//
#include <hip/hip_runtime.h>

#define B 16
#define N 1024
#define NF 128
#define NL 3
#define AH 64
#define HC 192   // NL*AH
#define FCH 128
#define NC 10
#define L2E 1.44269504088896f

typedef __attribute__((ext_vector_type(8))) short bf16x8;
typedef __attribute__((ext_vector_type(4))) float f32x4;
typedef __attribute__((ext_vector_type(4))) unsigned int u32x4;

static __device__ __forceinline__ unsigned short f2bf(float f) {
  unsigned int x = __builtin_bit_cast(unsigned int, f);
  return (unsigned short)((x + 0x7fffu + ((x >> 16) & 1u)) >> 16);   // RNE
}
static __device__ __forceinline__ float bf2f(unsigned short u) {
  unsigned int x = ((unsigned int)u) << 16;
  return __builtin_bit_cast(float, x);
}

// ---------------------------------------------------------------------------
// k_feat: 64 nodes/block; Ws staged per-layer into LDS with NEXT-LAYER
// register prefetch (T14); outputs h in FRAGMENT order h_f + f1/f2 f32
// pre-scaled by log2e. grid = 256 x 256, 2 blocks/CU.
// ---------------------------------------------------------------------------
__global__ __launch_bounds__(256, 2) void k_feat(
    const float* __restrict__ x, const float* __restrict__ Ws,
    const float* __restrict__ a1, const float* __restrict__ a2,
    unsigned short* __restrict__ h_f, float* __restrict__ f1g,
    float* __restrict__ f2g)
{
  __shared__ float xs[64][132];                  // 33.8KB; hlds overlays later
  __shared__ unsigned short wl[2][64][136];      // 34.8KB hi/lo for one layer
  unsigned short (*hlds)[72] = (unsigned short(*)[72])&xs[0][0];  // 27.6KB
  const int t = threadIdx.x;
  const int n0g = blockIdx.x * 64;
  const int gb = n0g >> 10, nl0 = n0g & 1023;
  const int wv = t >> 6, lane = t & 63;
  const int lr = lane & 15, lg = lane >> 4;
  const int lrow = wv * 16 + lr;
  const int wcol = t & 63, woct = t >> 6;        // W staging coords (4 tasks)

#define LOADW(R, L) {                                                         \
    _Pragma("unroll")                                                         \
    for (int p = 0; p < 4; ++p) {                                             \
      const int oct = p * 4 + woct;                                           \
      _Pragma("unroll")                                                       \
      for (int i = 0; i < 8; ++i)                                             \
        R[p][i] = Ws[((size_t)(L) * NF + oct * 8 + i) * AH + wcol];           \
    } }
#define WRITEW(R) {                                                           \
    _Pragma("unroll")                                                         \
    for (int p = 0; p < 4; ++p) {                                             \
      const int oct = p * 4 + woct;                                           \
      bf16x8 hv, lv;                                                          \
      _Pragma("unroll")                                                       \
      for (int i = 0; i < 8; ++i) {                                           \
        const unsigned short hi = f2bf(R[p][i]);                              \
        hv[i] = (short)hi;                                                    \
        lv[i] = (short)f2bf(R[p][i] - bf2f(hi));                              \
      }                                                                       \
      *(bf16x8*)&wl[0][wcol][oct * 8] = hv;                                   \
      *(bf16x8*)&wl[1][wcol][oct * 8] = lv;                                   \
    } }
#define MFMAL(L) {                                                            \
    _Pragma("unroll")                                                         \
    for (int n2 = 0; n2 < 4; ++n2) {                                          \
      const int n = (L) * 4 + n2;                                             \
      _Pragma("unroll")                                                       \
      for (int kf = 0; kf < 4; ++kf) {                                        \
        const bf16x8 whi = *(const bf16x8*)&wl[0][n2 * 16 + lr][kf * 32 + lg * 8]; \
        const bf16x8 wlo = *(const bf16x8*)&wl[1][n2 * 16 + lr][kf * 32 + lg * 8]; \
        acc[n] = __builtin_amdgcn_mfma_f32_16x16x32_bf16(xhi[kf], whi, acc[n], 0, 0, 0); \
        acc[n] = __builtin_amdgcn_mfma_f32_16x16x32_bf16(xhi[kf], wlo, acc[n], 0, 0, 0); \
        acc[n] = __builtin_amdgcn_mfma_f32_16x16x32_bf16(xlo[kf], whi, acc[n], 0, 0, 0); \
      }                                                                       \
    } }

  float wrA[4][8], wrB[4][8];
  LOADW(wrA, 0);                                 // layer-0 W in flight early

  // stage x coalesced: 2048 float4
  #pragma unroll
  for (int p = 0; p < 8; ++p) {
    const int q = p * 256 + t;
    const int row = q >> 5, c4 = (q & 31) * 4;
    *(float4*)&xs[row][c4] = *(const float4*)&x[(size_t)(n0g + row) * NF + c4];
  }
  __syncthreads();

  // per-lane x fragments + split-bf16 convert
  bf16x8 xhi[4], xlo[4];
  #pragma unroll
  for (int kf = 0; kf < 4; ++kf) {
    const float4 q0 = *(const float4*)&xs[lrow][kf * 32 + lg * 8];
    const float4 q1 = *(const float4*)&xs[lrow][kf * 32 + lg * 8 + 4];
    const float xv[8] = {q0.x, q0.y, q0.z, q0.w, q1.x, q1.y, q1.z, q1.w};
    #pragma unroll
    for (int e = 0; e < 8; ++e) {
      const unsigned short hi = f2bf(xv[e]);
      xhi[kf][e] = (short)hi;
      xlo[kf][e] = (short)f2bf(xv[e] - bf2f(hi));
    }
  }

  f32x4 acc[12];
  #pragma unroll
  for (int n = 0; n < 12; ++n) acc[n] = (f32x4){0.f, 0.f, 0.f, 0.f};

  // layer 0
  WRITEW(wrA);
  LOADW(wrB, 1);                                 // layer-1 W in flight
  __syncthreads();
  MFMAL(0);
  __syncthreads();
  // layer 1
  WRITEW(wrB);
  LOADW(wrA, 2);                                 // layer-2 W in flight
  __syncthreads();
  MFMAL(1);
  __syncthreads();
  // layer 2
  WRITEW(wrA);
  __syncthreads();
  MFMAL(2);

#undef LOADW
#undef WRITEW
#undef MFMAL

  // f1/f2 (exact f32), pre-scaled by log2e
  float s1[3][4], s2[3][4];
  #pragma unroll
  for (int l = 0; l < 3; ++l)
    #pragma unroll
    for (int r = 0; r < 4; ++r) { s1[l][r] = 0.f; s2[l][r] = 0.f; }
  #pragma unroll
  for (int n = 0; n < 12; ++n) {
    const int col = n * 16 + lr;
    const float a1v = a1[col] * L2E, a2v = a2[col] * L2E;
    const int l = n >> 2;
    #pragma unroll
    for (int r = 0; r < 4; ++r) {
      s1[l][r] += acc[n][r] * a1v;
      s2[l][r] += acc[n][r] * a2v;
    }
  }
  #pragma unroll
  for (int off = 1; off < 16; off <<= 1)
    #pragma unroll
    for (int l = 0; l < 3; ++l)
      #pragma unroll
      for (int r = 0; r < 4; ++r) {
        s1[l][r] += __shfl_xor(s1[l][r], off);
        s2[l][r] += __shfl_xor(s2[l][r], off);
      }
  if (lr == 0) {
    #pragma unroll
    for (int l = 0; l < 3; ++l)
      #pragma unroll
      for (int r = 0; r < 4; ++r) {
        const int rw = n0g + wv * 16 + lg * 4 + r;
        f1g[(size_t)l * (B * N) + rw] = s1[l][r];
        f2g[(size_t)l * (B * N) + rw] = s2[l][r];
      }
  }

  __syncthreads();                               // xs dead; hlds reuses it
  // pack bf16 -> LDS transpose (node-local index = wv*16+lg*4+r)
  #pragma unroll
  for (int n = 0; n < 12; ++n) {
    const int col = n * 16 + lr;
    #pragma unroll
    for (int rp = 0; rp < 2; ++rp) {
      const unsigned int pr = (unsigned int)f2bf(acc[n][rp * 2]) |
                              ((unsigned int)f2bf(acc[n][rp * 2 + 1]) << 16);
      *(unsigned int*)&hlds[col][wv * 16 + lg * 4 + rp * 2] = pr;
    }
  }
  __syncthreads();
  // fragment-order store
  #pragma unroll
  for (int p = 0; p < 6; ++p) {
    const int widx = p * 256 + t;                  // 0..1535
    const int lane_w = widx & 63;
    const int jb2 = (widx >> 6) & 1;
    const int n_w = (widx >> 7) & 3;
    const int l_w = widx >> 9;
    const int col = l_w * 64 + n_w * 16 + (lane_w & 15);
    const int jloc = jb2 * 32 + (lane_w >> 4) * 8;
    const size_t off =
        ((((size_t)(gb * 3 + l_w) * 4 + n_w) * 32 + (nl0 >> 5) + jb2) * 64 + lane_w) * 8;
    *(uint4*)&h_f[off] = *(const uint4*)&hlds[col][jloc];
  }
}

// ---------------------------------------------------------------------------
// k_att: fused 3-layer GAT attention + MFMA PV + ones-column denominator +
// relu + pool. Phase-staggered circular j-loop (convoy breaker), adj staged
// as u16 0xFFFF/0 masks (bitwise AND, no cvt), 128-j segments with
// full-segment staging slack. grid = 1024 x 192 (3 waves = layers).
// ---------------------------------------------------------------------------
__global__ __launch_bounds__(192, 3) void k_att(
    const float* __restrict__ adj, const unsigned short* __restrict__ h_f,
    const float* __restrict__ f1, const float* __restrict__ f2,
    float* __restrict__ pooled)
{
  const int bid = blockIdx.x;
  const int blk = (bid & 7) * 128 + (bid >> 3);  // 8 XCDs x 128: 2 batches/XCD
  const int b = blk >> 6;
  const int i0 = (blk & 63) * 16;
  const int ph = ((bid * 5) & 7) * 128;          // per-block phase stagger
  const int t = threadIdx.x;
  const int l = t >> 6, lane = t & 63;
  const int lr = lane & 15, lg = lane >> 4;

  __shared__ float uvt[NL][2][N];                // 24 KB u/v tables
  __shared__ unsigned short adjm[2][16][136];    // 8.5 KB u16 mask tiles

  // ---- prologue: u/v tables + full-N unmasked max (wave l = layer l) ----
  const float* f2p = f2 + (size_t)l * (B * N) + b * N;
  float mx = -1e30f;
  #pragma unroll
  for (int ch = 0; ch < 4; ++ch) {
    const int jb = ch * 256 + lane * 4;
    const float4 q = *(const float4*)&f2p[jb];
    mx = fmaxf(mx, fmaxf(fmaxf(q.x, q.y), fmaxf(q.z, q.w)));
    *(float4*)&uvt[l][0][jb] =
        (float4){exp2f(q.x), exp2f(q.y), exp2f(q.z), exp2f(q.w)};
    *(float4*)&uvt[l][1][jb] =
        (float4){exp2f(0.2f * q.x), exp2f(0.2f * q.y), exp2f(0.2f * q.z), exp2f(0.2f * q.w)};
  }
  #pragma unroll
  for (int off = 1; off < 64; off <<= 1) mx = fmaxf(mx, __shfl_xor(mx, off));

  const float f1r = f1[(size_t)l * (B * N) + b * N + i0 + lr];
  const float tts = f1r + mx;
  const float sr = fmaxf(tts, 0.f) + 0.2f * fminf(tts, 0.f);  // valid upper bound
  const float A = exp2f(f1r - sr);
  const float C = exp2f(0.2f * f1r - sr);

  const float* adjb = adj + ((size_t)(b * N + i0)) * N;   // 16 rows x N
  const unsigned short* hfb = h_f + ((size_t)(b * 3 + l)) * 65536;
  const float* ut = &uvt[l][0][0];
  const float* vt = &uvt[l][1][0];
  const bf16x8 ones = {(short)0x3F80, (short)0x3F80, (short)0x3F80, (short)0x3F80,
                       (short)0x3F80, (short)0x3F80, (short)0x3F80, (short)0x3F80};

  // staging coords: 512 float4 tasks per 16x128 segment
  const int s_r = t >> 5, s_c = (t & 31) * 4;    // rows r, r+6, r+12(t<128)

  f32x4 acc[4];
  #pragma unroll
  for (int n = 0; n < 4; ++n) acc[n] = (f32x4){0.f, 0.f, 0.f, 0.f};
  f32x4 accd = (f32x4){0.f, 0.f, 0.f, 0.f};

#define PACK2(X, Y) (((X) ? 0xFFFFu : 0u) | ((Y) ? 0xFFFF0000u : 0u))

#define ISSUE(S0, S1, S2, J) {                                                \
    const int jn = (J) & (N - 1);                                             \
    S0 = *(const uint4*)&adjb[(size_t)s_r * N + jn + s_c];                    \
    S1 = *(const uint4*)&adjb[(size_t)(s_r + 6) * N + jn + s_c];              \
    if (t < 128) S2 = *(const uint4*)&adjb[(size_t)(s_r + 12) * N + jn + s_c];\
  }
#define WRITEM(S0, S1, S2, SB) {                                              \
    *(uint2*)&adjm[SB][s_r][s_c] =                                            \
        (uint2){PACK2(S0.x, S0.y), PACK2(S0.z, S0.w)};                        \
    *(uint2*)&adjm[SB][s_r + 6][s_c] =                                        \
        (uint2){PACK2(S1.x, S1.y), PACK2(S1.z, S1.w)};                        \
    if (t < 128) *(uint2*)&adjm[SB][s_r + 12][s_c] =                          \
        (uint2){PACK2(S2.x, S2.y), PACK2(S2.z, S2.w)};                        \
  }

#define LOADJ(BUF, J) {                                                       \
    const int jj = (J) & (N - 1);                                             \
    _Pragma("unroll")                                                         \
    for (int q = 0; q < 8; ++q) {                                             \
      const int ks = q >> 2, n = q & 3;                                       \
      BUF[q] = *(const bf16x8*)&hfb[(((size_t)n * 32 + (jj >> 5) + ks) * 64 + \
                                     lane) * 8];                              \
    } }

#define COMPJ(BUF, SB, J, TOFF) {                                             \
    _Pragma("unroll")                                                         \
    for (int ks = 0; ks < 2; ++ks) {                                          \
      const int kb = ((J) & (N - 1)) + ks * 32 + lg * 8;                      \
      const float4 u0 = *(const float4*)&ut[kb];                              \
      const float4 u1 = *(const float4*)&ut[kb + 4];                          \
      const float4 v0 = *(const float4*)&vt[kb];                              \
      const float4 v1 = *(const float4*)&vt[kb + 4];                          \
      const uint4 mk = *(const uint4*)&adjm[SB][lr][(TOFF) + ks * 32 + lg * 8];\
      const float uu[8] = {u0.x, u0.y, u0.z, u0.w, u1.x, u1.y, u1.z, u1.w};   \
      const float vv[8] = {v0.x, v0.y, v0.z, v0.w, v1.x, v1.y, v1.z, v1.w};   \
      const unsigned int mka[4] = {mk.x, mk.y, mk.z, mk.w};                   \
      unsigned int pk[4];                                                     \
      _Pragma("unroll")                                                       \
      for (int ep = 0; ep < 4; ++ep) {                                        \
        unsigned int pr[2];                                                   \
        _Pragma("unroll")                                                     \
        for (int h = 0; h < 2; ++h) {                                         \
          const int e = ep * 2 + h;                                           \
          /* leaky(t)=max(t,0.2t); exp2 monotone => P=max(A*u, C*v) */        \
          const float p = fmaxf(A * uu[e], C * vv[e]);                        \
          pr[h] = __builtin_bit_cast(unsigned int, p) + 0x8000u;              \
        }                                                                     \
        pk[ep] = __builtin_amdgcn_perm(pr[1], pr[0], 0x07060302u) & mka[ep];  \
      }                                                                       \
      const u32x4 pkv = {pk[0], pk[1], pk[2], pk[3]};                         \
      const bf16x8 av = __builtin_bit_cast(bf16x8, pkv);                      \
      _Pragma("unroll")                                                       \
      for (int n = 0; n < 4; ++n)                                             \
        acc[n] = __builtin_amdgcn_mfma_f32_16x16x32_bf16(av, BUF[ks * 4 + n], \
                                                         acc[n], 0, 0, 0);    \
      accd = __builtin_amdgcn_mfma_f32_16x16x32_bf16(av, ones, accd, 0, 0, 0);\
    } }

#define SBAR __builtin_amdgcn_sched_barrier(0)

  bf16x8 bA[8], bB[8];
  uint4 A0, A1, A2, B0, B1, B2;

  // pipeline fill: seg0 -> LDS buf0 now; seg1 in flight in set A
  ISSUE(A0, A1, A2, ph);
  WRITEM(A0, A1, A2, 0);
  ISSUE(A0, A1, A2, ph + 128);
  LOADJ(bA, ph);
  __syncthreads();                               // uvt + adjm[0] ready

  for (int s = 0; s < 8; s += 2) {
    const int jp = ph + s * 128;
    // ---- even segment: compute jp, jp+64 from buf0 ----
    ISSUE(B0, B1, B2, jp + 256);                 // seg s+2 into set B
    LOADJ(bB, jp + 64);
    SBAR;
    COMPJ(bA, 0, jp, 0);
    SBAR;
    LOADJ(bA, jp + 128);
    SBAR;
    COMPJ(bB, 0, jp + 64, 64);
    SBAR;
    WRITEM(A0, A1, A2, 1);                       // seg s+1 (issued 1 seg ago)
    __syncthreads();
    // ---- odd segment: compute jp+128, jp+192 from buf1 ----
    ISSUE(A0, A1, A2, jp + 384);                 // seg s+3 into set A
    LOADJ(bB, jp + 192);
    SBAR;
    COMPJ(bA, 1, jp + 128, 0);
    SBAR;
    LOADJ(bA, jp + 256);
    SBAR;
    COMPJ(bB, 1, jp + 192, 64);
    SBAR;
    WRITEM(B0, B1, B2, 0);                       // seg s+2 (issued 1 seg ago)
    __syncthreads();
  }
#undef PACK2
#undef ISSUE
#undef WRITEM
#undef LOADJ
#undef COMPJ
#undef SBAR

  // epilogue: rows i0+lg*4+r owned by this lane's acc regs; denom from accd
  float dn[4];
  #pragma unroll
  for (int r = 0; r < 4; ++r) dn[r] = 1.f / fmaxf(accd[r], 1e-37f);

  #pragma unroll
  for (int n = 0; n < 4; ++n) {
    float csum = 0.f;
    #pragma unroll
    for (int r = 0; r < 4; ++r) csum += fmaxf(acc[n][r] * dn[r], 0.f);
    csum += __shfl_xor(csum, 16);
    csum += __shfl_xor(csum, 32);
    if (lg == 0) atomicAdd(&pooled[b * HC + l * 64 + n * 16 + lr], csum);
  }
}

// ---------------------------------------------------------------------------
// k_head: mean + FC1(relu) + FC2 + softmax.  grid = B.
// ---------------------------------------------------------------------------
__global__ __launch_bounds__(192) void k_head(
    const float* __restrict__ pooled_sums, const float* __restrict__ W1,
    const float* __restrict__ b1, const float* __restrict__ W2,
    const float* __restrict__ b2, float* __restrict__ out)
{
  const int b = blockIdx.x, t = threadIdx.x;
  __shared__ float pooled[HC];
  __shared__ float z[FCH];
  __shared__ float logits[NC];

  if (t < HC) pooled[t] = pooled_sums[b * HC + t] * (1.f / (float)N);
  __syncthreads();

  if (t < FCH) {
    float a = b1[t];
    #pragma unroll 4
    for (int f = 0; f < HC; ++f) a += pooled[f] * W1[(size_t)f * FCH + t];
    z[t] = a > 0.f ? a : 0.f;
  }
  __syncthreads();

  if (t < NC) {
    float a = b2[t];
    #pragma unroll 4
    for (int f = 0; f < FCH; ++f) a += z[f] * W2[(size_t)f * NC + t];
    logits[t] = a;
  }
  __syncthreads();

  if (t == 0) {
    float mxl = logits[0];
    for (int c = 1; c < NC; ++c) mxl = fmaxf(mxl, logits[c]);
    float e[NC], sum = 0.f;
    for (int c = 0; c < NC; ++c) { e[c] = __expf(logits[c] - mxl); sum += e[c]; }
    const float inv = 1.f / sum;
    for (int c = 0; c < NC; ++c) out[b * NC + c] = e[c] * inv;
  }
}

// ---------------------------------------------------------------------------
extern "C" void kernel_launch(void* const* d_in, const int* in_sizes, int n_in,
                              void* d_out, int out_size, void* d_ws, size_t ws_size,
                              hipStream_t stream)
{
  const float* x   = (const float*)d_in[0];
  const float* adj = (const float*)d_in[1];
  const float* Ws  = (const float*)d_in[2];
  const float* a1  = (const float*)d_in[3];
  const float* a2  = (const float*)d_in[4];
  const float* W1  = (const float*)d_in[5];
  const float* b1  = (const float*)d_in[6];
  const float* W2  = (const float*)d_in[7];
  const float* b2  = (const float*)d_in[8];
  float* out = (float*)d_out;

  // workspace layout (16B aligned chunks)
  unsigned short* h_f   = (unsigned short*)d_ws;                       // 6.29 MB
  float*          f1    = (float*)(h_f + (size_t)B * HC * N);          // 196 KB
  float*          f2    = f1 + (size_t)NL * B * N;                     // 196 KB
  float*          pooled= f2 + (size_t)NL * B * N;                     // 12 KB

  hipMemsetAsync(pooled, 0, (size_t)B * HC * sizeof(float), stream);
  k_feat<<<256, 256, 0, stream>>>(x, Ws, a1, a2, h_f, f1, f2);
  k_att <<<1024, 192, 0, stream>>>(adj, h_f, f1, f2, pooled);
  k_head<<<B, 192, 0, stream>>>(pooled, W1, b1, W2, b2, out);
}